// Round 1
// baseline (841.126 us; speedup 1.0000x reference)
//
#include <hip/hip_runtime.h>

#define NN 40000
#define NE 640000
#define HID 128
#define NL 5

// ---------------- encoder: h[n][k] = x[n][:7] . encW[k][:7] + encb[k] ----------------
__global__ void encoder_kernel(const float* __restrict__ x, const float* __restrict__ W,
                               const float* __restrict__ b, float* __restrict__ h) {
  int gid = blockIdx.x * blockDim.x + threadIdx.x;
  if (gid >= NN * HID) return;
  int n = gid >> 7, k = gid & 127;
  const float* xp = x + n * 7;
  const float* wp = W + k * 7;
  float acc = b[k];
#pragma unroll
  for (int i = 0; i < 7; ++i) acc += xp[i] * wp[i];
  h[gid] = acc;
}

// ---------------- CSR build ----------------
__global__ void hist_kernel(const int* __restrict__ dst, int* __restrict__ cnt) {
  int e = blockIdx.x * blockDim.x + threadIdx.x;
  if (e < NE) atomicAdd(&cnt[dst[e]], 1);
}

__global__ void scan_kernel(const int* __restrict__ cnt, int* __restrict__ row_ptr) {
  __shared__ int part[1024];
  int t = threadIdx.x;
  const int C = (NN + 1023) / 1024;  // 40
  int base = t * C;
  int s = 0;
  for (int i = 0; i < C; ++i) { int idx = base + i; if (idx < NN) s += cnt[idx]; }
  part[t] = s;
  __syncthreads();
  for (int off = 1; off < 1024; off <<= 1) {
    int v = (t >= off) ? part[t - off] : 0;
    __syncthreads();
    part[t] += v;
    __syncthreads();
  }
  int run = (t == 0) ? 0 : part[t - 1];
  for (int i = 0; i < C; ++i) {
    int idx = base + i;
    if (idx < NN) { row_ptr[idx] = run; run += cnt[idx]; }
  }
  if (t == 1023) row_ptr[NN] = part[1023];
}

__global__ void scatter_kernel(const int* __restrict__ src, const int* __restrict__ dst,
                               const float* __restrict__ dist,
                               const int* __restrict__ row_ptr, int* __restrict__ fill,
                               int* __restrict__ csr_src, float* __restrict__ csr_w) {
  int e = blockIdx.x * blockDim.x + threadIdx.x;
  if (e >= NE) return;
  int d = dst[e];
  int pos = row_ptr[d] + atomicAdd(&fill[d], 1);
  csr_src[pos] = src[e];
  float dd = dist[e] + 1e-6f;
  csr_w[pos] = 1.0f / (dd * dd);
}

__global__ void wsum_kernel(const int* __restrict__ row_ptr, const float* __restrict__ csr_w,
                            float* __restrict__ wsum) {
  int n = blockIdx.x * blockDim.x + threadIdx.x;
  if (n >= NN) return;
  int s = row_ptr[n], e = row_ptr[n + 1];
  float acc = 0.f;
  for (int i = s; i < e; ++i) acc += csr_w[i];
  wsum[n] = acc;
}

// ---------------- per-layer: aggregate (wave per node) ----------------
__global__ void aggregate_kernel(const float* __restrict__ h, const int* __restrict__ row_ptr,
                                 const int* __restrict__ csr_src, const float* __restrict__ csr_w,
                                 float* __restrict__ agg) {
  int wid = (blockIdx.x * blockDim.x + threadIdx.x) >> 6;
  int lane = threadIdx.x & 63;
  if (wid >= NN) return;
  int s = row_ptr[wid], e = row_ptr[wid + 1];
  float a0 = 0.f, a1 = 0.f;
  for (int i = s; i < e; ++i) {
    int sn = csr_src[i];
    float w = csr_w[i];
    const float* hp = h + sn * HID;
    a0 += w * hp[lane];
    a1 += w * hp[lane + 64];
  }
  agg[wid * HID + lane] = a0;
  agg[wid * HID + 64 + lane] = a1;
}

// ---------------- per-layer: h = relu(agg @ W^T + b * wsum) ----------------
// block = 256 threads, 16 nodes per block (40000 % 16 == 0 -> no bounds checks)
__global__ void __launch_bounds__(256) linear_kernel(const float* __restrict__ agg,
                                                     const float* __restrict__ wsum,
                                                     const float* __restrict__ W,
                                                     const float* __restrict__ b,
                                                     float* __restrict__ h) {
  __shared__ float sA[16][HID];
  int t = threadIdx.x;
  int node0 = blockIdx.x * 16;
#pragma unroll
  for (int p = 0; p < 8; ++p) {
    int idx = p * 256 + t;
    int n = idx >> 7, j = idx & 127;
    sA[n][j] = agg[(node0 + n) * HID + j];
  }
  __syncthreads();
  int k = t & 127;
  int ng = (t >> 7) * 8;  // 0 or 8
  float acc[8] = {0.f, 0.f, 0.f, 0.f, 0.f, 0.f, 0.f, 0.f};
  const float* Wk = W + k * HID;
  for (int j = 0; j < HID; j += 4) {
    float4 w4 = *reinterpret_cast<const float4*>(Wk + j);
#pragma unroll
    for (int i = 0; i < 8; ++i) {
      float4 a4 = *reinterpret_cast<const float4*>(&sA[ng + i][j]);
      acc[i] += w4.x * a4.x + w4.y * a4.y + w4.z * a4.z + w4.w * a4.w;
    }
  }
  float bk = b[k];
#pragma unroll
  for (int i = 0; i < 8; ++i) {
    int n = node0 + ng + i;
    float v = acc[i] + bk * wsum[n];
    h[n * HID + k] = fmaxf(v, 0.f);
  }
}

// ---------------- cluster softmax head (wave per node) ----------------
__global__ void cluster_kernel(const float* __restrict__ h, const float* __restrict__ cW,
                               const float* __restrict__ cb, float* __restrict__ out) {
  int wid = (blockIdx.x * blockDim.x + threadIdx.x) >> 6;
  int lane = threadIdx.x & 63;
  if (wid >= NN) return;
  float h0 = h[wid * HID + lane];
  float h1 = h[wid * HID + 64 + lane];
  float logit[3];
#pragma unroll
  for (int c = 0; c < 3; ++c) {
    float p = h0 * cW[c * HID + lane] + h1 * cW[c * HID + 64 + lane];
#pragma unroll
    for (int off = 32; off > 0; off >>= 1) p += __shfl_xor(p, off, 64);
    logit[c] = p + cb[c];
  }
  if (lane == 0) {
    float m = fmaxf(logit[0], fmaxf(logit[1], logit[2]));
    float e0 = expf(logit[0] - m), e1 = expf(logit[1] - m), e2 = expf(logit[2] - m);
    float inv = 1.0f / (e0 + e1 + e2);
    out[wid * 3 + 0] = e0 * inv;
    out[wid * 3 + 1] = e1 * inv;
    out[wid * 3 + 2] = e2 * inv;
  }
}

// ---------------- energy head ----------------
__global__ void colsum_kernel(const float* __restrict__ h, float* __restrict__ colsum) {
  int t = threadIdx.x;  // 0..127 (one column each)
  int base = blockIdx.x * 256;
  int end = base + 256 < NN ? base + 256 : NN;
  float acc = 0.f;
  for (int n = base; n < end; ++n) acc += h[n * HID + t];
  atomicAdd(&colsum[t], acc);
}

__global__ void energy_kernel(const float* __restrict__ colsum, const float* __restrict__ eW,
                              const float* __restrict__ eb, float* __restrict__ out) {
  __shared__ float red[2];
  int t = threadIdx.x;  // 128 threads
  float v = colsum[t] * (1.0f / NN) * eW[t];
#pragma unroll
  for (int off = 32; off > 0; off >>= 1) v += __shfl_xor(v, off, 64);
  if ((t & 63) == 0) red[t >> 6] = v;
  __syncthreads();
  if (t == 0) {
    float e = red[0] + red[1] + eb[0];
    out[NN * 3] = e;
    out[NN * 3 + 1] = (e < -1.0f) ? 1.0f : 0.0f;
  }
}

extern "C" void kernel_launch(void* const* d_in, const int* in_sizes, int n_in,
                              void* d_out, int out_size, void* d_ws, size_t ws_size,
                              hipStream_t stream) {
  const float* x    = (const float*)d_in[0];
  const int*   ei   = (const int*)d_in[1];
  const float* dist = (const float*)d_in[2];
  const float* encW = (const float*)d_in[3];
  const float* encb = (const float*)d_in[4];
  const float* convW = (const float*)d_in[5];
  const float* convb = (const float*)d_in[6];
  const float* cW   = (const float*)d_in[7];
  const float* cb   = (const float*)d_in[8];
  const float* eW   = (const float*)d_in[9];
  const float* eb   = (const float*)d_in[10];
  float* out = (float*)d_out;

  // workspace layout (bytes)
  char* ws = (char*)d_ws;
  float* h       = (float*)(ws + 0);           // 20,480,000
  float* agg     = (float*)(ws + 20480000);    // 20,480,000
  int*   csr_src = (int*)  (ws + 40960000);    //  2,560,000
  float* csr_w   = (float*)(ws + 43520000);    //  2,560,000
  int*   row_ptr = (int*)  (ws + 46080000);    //    160,004 (padded to 160,064)
  int*   cnt     = (int*)  (ws + 46240064);    //    160,000
  int*   fill    = (int*)  (ws + 46400064);    //    160,000
  float* wsum    = (float*)(ws + 46560064);    //    160,000
  float* colsum  = (float*)(ws + 46720064);    //        512
  if (ws_size < (size_t)46720576) return;  // insufficient scratch — fail visibly

  const int* srcI = ei;
  const int* dstI = ei + NE;

  // zero cnt + fill (contiguous) and colsum
  hipMemsetAsync(cnt, 0, 320000, stream);
  hipMemsetAsync(colsum, 0, 512, stream);

  encoder_kernel<<<(NN * HID + 255) / 256, 256, 0, stream>>>(x, encW, encb, h);

  hist_kernel<<<(NE + 255) / 256, 256, 0, stream>>>(dstI, cnt);
  scan_kernel<<<1, 1024, 0, stream>>>(cnt, row_ptr);
  scatter_kernel<<<(NE + 255) / 256, 256, 0, stream>>>(srcI, dstI, dist, row_ptr, fill,
                                                       csr_src, csr_w);
  wsum_kernel<<<(NN + 255) / 256, 256, 0, stream>>>(row_ptr, csr_w, wsum);

  for (int l = 0; l < NL; ++l) {
    aggregate_kernel<<<(NN * 64 + 255) / 256, 256, 0, stream>>>(h, row_ptr, csr_src, csr_w, agg);
    linear_kernel<<<NN / 16, 256, 0, stream>>>(agg, wsum, convW + (size_t)l * HID * HID,
                                               convb + (size_t)l * HID, h);
  }

  cluster_kernel<<<(NN * 64 + 255) / 256, 256, 0, stream>>>(h, cW, cb, out);
  colsum_kernel<<<(NN + 255) / 256, 128, 0, stream>>>(h, colsum);
  energy_kernel<<<1, 128, 0, stream>>>(colsum, eW, eb, out);
}

// Round 2
// 773.969 us; speedup vs baseline: 1.0868x; 1.0868x over previous
//
#include <hip/hip_runtime.h>

#define NN 40000
#define NE 640000
#define HID 128
#define NL 5
#define NBLK 157  // ceil(40000/256)

// ---------------- encoder: h[n][k] = x[n][:7] . encW[k][:7] + encb[k] ----------------
__global__ void encoder_kernel(const float* __restrict__ x, const float* __restrict__ W,
                               const float* __restrict__ b, float* __restrict__ h) {
  int gid = blockIdx.x * blockDim.x + threadIdx.x;
  if (gid >= NN * HID) return;
  int n = gid >> 7, k = gid & 127;
  const float* xp = x + n * 7;
  const float* wp = W + k * 7;
  float acc = b[k];
#pragma unroll
  for (int i = 0; i < 7; ++i) acc += xp[i] * wp[i];
  h[gid] = acc;
}

// ---------------- CSR build ----------------
__global__ void hist_kernel(const int* __restrict__ dst, int* __restrict__ cnt) {
  int e = blockIdx.x * blockDim.x + threadIdx.x;
  if (e < NE) atomicAdd(&cnt[dst[e]], 1);
}

// stage 1: per-block sums of cnt
__global__ void partial_kernel(const int* __restrict__ cnt, int* __restrict__ blocksum) {
  __shared__ int red[4];
  int t = threadIdx.x;
  int idx = blockIdx.x * 256 + t;
  int v = idx < NN ? cnt[idx] : 0;
#pragma unroll
  for (int off = 32; off > 0; off >>= 1) v += __shfl_xor(v, off, 64);
  if ((t & 63) == 0) red[t >> 6] = v;
  __syncthreads();
  if (t == 0) blocksum[blockIdx.x] = red[0] + red[1] + red[2] + red[3];
}

// stage 2: exclusive scan of the 157 block sums (single tiny block)
__global__ void scan_small_kernel(const int* __restrict__ blocksum, int* __restrict__ blockoff,
                                  int* __restrict__ row_ptr) {
  __shared__ int sh[256];
  int t = threadIdx.x;
  int v = t < NBLK ? blocksum[t] : 0;
  sh[t] = v;
  __syncthreads();
  for (int off = 1; off < 256; off <<= 1) {
    int u = (t >= off) ? sh[t - off] : 0;
    __syncthreads();
    sh[t] += u;
    __syncthreads();
  }
  if (t < NBLK) blockoff[t] = sh[t] - v;
  if (t == 255) row_ptr[NN] = sh[255];
}

// stage 3: per-block exclusive scan + block offset -> row_ptr
__global__ void rowptr_kernel(const int* __restrict__ cnt, const int* __restrict__ blockoff,
                              int* __restrict__ row_ptr) {
  __shared__ int sh[256];
  int t = threadIdx.x;
  int idx = blockIdx.x * 256 + t;
  int v = idx < NN ? cnt[idx] : 0;
  sh[t] = v;
  __syncthreads();
  for (int off = 1; off < 256; off <<= 1) {
    int u = (t >= off) ? sh[t - off] : 0;
    __syncthreads();
    sh[t] += u;
    __syncthreads();
  }
  if (idx < NN) row_ptr[idx] = blockoff[blockIdx.x] + sh[t] - v;
}

__global__ void scatter_kernel(const int* __restrict__ src, const int* __restrict__ dst,
                               const float* __restrict__ dist,
                               const int* __restrict__ row_ptr, int* __restrict__ fill,
                               int* __restrict__ csr_src, float* __restrict__ csr_w) {
  int e = blockIdx.x * blockDim.x + threadIdx.x;
  if (e >= NE) return;
  int d = dst[e];
  int pos = row_ptr[d] + atomicAdd(&fill[d], 1);
  csr_src[pos] = src[e];
  float dd = dist[e] + 1e-6f;
  csr_w[pos] = 1.0f / (dd * dd);
}

__global__ void wsum_kernel(const int* __restrict__ row_ptr, const float* __restrict__ csr_w,
                            float* __restrict__ wsum) {
  int n = blockIdx.x * blockDim.x + threadIdx.x;
  if (n >= NN) return;
  int s = row_ptr[n], e = row_ptr[n + 1];
  float acc = 0.f;
  for (int i = s; i < e; ++i) acc += csr_w[i];
  wsum[n] = acc;
}

// ---------------- per-layer: aggregate (wave per node, float2 gather) ----------------
__global__ void aggregate_kernel(const float* __restrict__ h, const int* __restrict__ row_ptr,
                                 const int* __restrict__ csr_src, const float* __restrict__ csr_w,
                                 float* __restrict__ agg) {
  int wid = (blockIdx.x * blockDim.x + threadIdx.x) >> 6;
  int lane = threadIdx.x & 63;
  if (wid >= NN) return;
  int s = row_ptr[wid], e = row_ptr[wid + 1];
  float ax = 0.f, ay = 0.f;
  for (int i = s; i < e; ++i) {
    int sn = csr_src[i];
    float w = csr_w[i];
    float2 hv = *reinterpret_cast<const float2*>(h + sn * HID + lane * 2);
    ax += w * hv.x;
    ay += w * hv.y;
  }
  float2 r = {ax, ay};
  *reinterpret_cast<float2*>(agg + wid * HID + lane * 2) = r;
}

// ---------------- per-layer: h = relu(agg @ W^T + b * wsum) ----------------
__global__ void __launch_bounds__(256) linear_kernel(const float* __restrict__ agg,
                                                     const float* __restrict__ wsum,
                                                     const float* __restrict__ W,
                                                     const float* __restrict__ b,
                                                     float* __restrict__ h) {
  __shared__ float sA[16][HID];
  int t = threadIdx.x;
  int node0 = blockIdx.x * 16;
#pragma unroll
  for (int p = 0; p < 8; ++p) {
    int idx = p * 256 + t;
    int n = idx >> 7, j = idx & 127;
    sA[n][j] = agg[(node0 + n) * HID + j];
  }
  __syncthreads();
  int k = t & 127;
  int ng = (t >> 7) * 8;  // 0 or 8
  float acc[8] = {0.f, 0.f, 0.f, 0.f, 0.f, 0.f, 0.f, 0.f};
  const float* Wk = W + k * HID;
  for (int j = 0; j < HID; j += 4) {
    float4 w4 = *reinterpret_cast<const float4*>(Wk + j);
#pragma unroll
    for (int i = 0; i < 8; ++i) {
      float4 a4 = *reinterpret_cast<const float4*>(&sA[ng + i][j]);
      acc[i] += w4.x * a4.x + w4.y * a4.y + w4.z * a4.z + w4.w * a4.w;
    }
  }
  float bk = b[k];
#pragma unroll
  for (int i = 0; i < 8; ++i) {
    int n = node0 + ng + i;
    float v = acc[i] + bk * wsum[n];
    h[n * HID + k] = fmaxf(v, 0.f);
  }
}

// ---------------- cluster softmax head (wave per node) ----------------
__global__ void cluster_kernel(const float* __restrict__ h, const float* __restrict__ cW,
                               const float* __restrict__ cb, float* __restrict__ out) {
  int wid = (blockIdx.x * blockDim.x + threadIdx.x) >> 6;
  int lane = threadIdx.x & 63;
  if (wid >= NN) return;
  float h0 = h[wid * HID + lane];
  float h1 = h[wid * HID + 64 + lane];
  float logit[3];
#pragma unroll
  for (int c = 0; c < 3; ++c) {
    float p = h0 * cW[c * HID + lane] + h1 * cW[c * HID + 64 + lane];
#pragma unroll
    for (int off = 32; off > 0; off >>= 1) p += __shfl_xor(p, off, 64);
    logit[c] = p + cb[c];
  }
  if (lane == 0) {
    float m = fmaxf(logit[0], fmaxf(logit[1], logit[2]));
    float e0 = expf(logit[0] - m), e1 = expf(logit[1] - m), e2 = expf(logit[2] - m);
    float inv = 1.0f / (e0 + e1 + e2);
    out[wid * 3 + 0] = e0 * inv;
    out[wid * 3 + 1] = e1 * inv;
    out[wid * 3 + 2] = e2 * inv;
  }
}

// ---------------- energy head ----------------
__global__ void colsum_kernel(const float* __restrict__ h, float* __restrict__ colsum) {
  int t = threadIdx.x;  // 0..127 (one column each)
  int base = blockIdx.x * 256;
  int end = base + 256 < NN ? base + 256 : NN;
  float acc = 0.f;
  for (int n = base; n < end; ++n) acc += h[n * HID + t];
  atomicAdd(&colsum[t], acc);
}

__global__ void energy_kernel(const float* __restrict__ colsum, const float* __restrict__ eW,
                              const float* __restrict__ eb, float* __restrict__ out) {
  __shared__ float red[2];
  int t = threadIdx.x;  // 128 threads
  float v = colsum[t] * (1.0f / NN) * eW[t];
#pragma unroll
  for (int off = 32; off > 0; off >>= 1) v += __shfl_xor(v, off, 64);
  if ((t & 63) == 0) red[t >> 6] = v;
  __syncthreads();
  if (t == 0) {
    float e = red[0] + red[1] + eb[0];
    out[NN * 3] = e;
    out[NN * 3 + 1] = (e < -1.0f) ? 1.0f : 0.0f;
  }
}

extern "C" void kernel_launch(void* const* d_in, const int* in_sizes, int n_in,
                              void* d_out, int out_size, void* d_ws, size_t ws_size,
                              hipStream_t stream) {
  const float* x    = (const float*)d_in[0];
  const int*   ei   = (const int*)d_in[1];
  const float* dist = (const float*)d_in[2];
  const float* encW = (const float*)d_in[3];
  const float* encb = (const float*)d_in[4];
  const float* convW = (const float*)d_in[5];
  const float* convb = (const float*)d_in[6];
  const float* cW   = (const float*)d_in[7];
  const float* cb   = (const float*)d_in[8];
  const float* eW   = (const float*)d_in[9];
  const float* eb   = (const float*)d_in[10];
  float* out = (float*)d_out;

  // workspace layout (bytes)
  char* ws = (char*)d_ws;
  float* h       = (float*)(ws + 0);           // 20,480,000
  float* agg     = (float*)(ws + 20480000);    // 20,480,000
  int*   csr_src = (int*)  (ws + 40960000);    //  2,560,000
  float* csr_w   = (float*)(ws + 43520000);    //  2,560,000
  int*   row_ptr = (int*)  (ws + 46080000);    //    160,004 (padded to 160,064)
  int*   cnt     = (int*)  (ws + 46240064);    //    160,000
  int*   fill    = (int*)  (ws + 46400064);    //    160,000
  float* wsum    = (float*)(ws + 46560064);    //    160,000
  float* colsum  = (float*)(ws + 46720064);    //        512
  if (ws_size < (size_t)46720576) return;  // insufficient scratch — fail visibly

  // agg is unused until the first aggregate_kernel -> carve scan scratch from it
  int* blocksum = (int*)agg;          // NBLK ints
  int* blockoff = (int*)agg + 512;    // NBLK ints

  const int* srcI = ei;
  const int* dstI = ei + NE;

  // zero cnt + fill (contiguous) and colsum
  hipMemsetAsync(cnt, 0, 320000, stream);
  hipMemsetAsync(colsum, 0, 512, stream);

  encoder_kernel<<<(NN * HID + 255) / 256, 256, 0, stream>>>(x, encW, encb, h);

  hist_kernel<<<(NE + 255) / 256, 256, 0, stream>>>(dstI, cnt);
  partial_kernel<<<NBLK, 256, 0, stream>>>(cnt, blocksum);
  scan_small_kernel<<<1, 256, 0, stream>>>(blocksum, blockoff, row_ptr);
  rowptr_kernel<<<NBLK, 256, 0, stream>>>(cnt, blockoff, row_ptr);
  scatter_kernel<<<(NE + 255) / 256, 256, 0, stream>>>(srcI, dstI, dist, row_ptr, fill,
                                                       csr_src, csr_w);
  wsum_kernel<<<(NN + 255) / 256, 256, 0, stream>>>(row_ptr, csr_w, wsum);

  for (int l = 0; l < NL; ++l) {
    aggregate_kernel<<<(NN * 64 + 255) / 256, 256, 0, stream>>>(h, row_ptr, csr_src, csr_w, agg);
    linear_kernel<<<NN / 16, 256, 0, stream>>>(agg, wsum, convW + (size_t)l * HID * HID,
                                               convb + (size_t)l * HID, h);
  }

  cluster_kernel<<<(NN * 64 + 255) / 256, 256, 0, stream>>>(h, cW, cb, out);
  colsum_kernel<<<(NN + 255) / 256, 128, 0, stream>>>(h, colsum);
  energy_kernel<<<1, 128, 0, stream>>>(colsum, eW, eb, out);
}

// Round 3
// 684.277 us; speedup vs baseline: 1.2292x; 1.1311x over previous
//
#include <hip/hip_runtime.h>

#define NN 40000
#define NE 640000
#define HID 128
#define NL 5
#define NBLK 157  // ceil(40000/256)

// ---------------- encoder: h[n][k] = x[n][:7] . encW[k][:7] + encb[k] ----------------
__global__ void encoder_kernel(const float* __restrict__ x, const float* __restrict__ W,
                               const float* __restrict__ b, float* __restrict__ h) {
  int gid = blockIdx.x * blockDim.x + threadIdx.x;
  if (gid >= NN * HID) return;
  int n = gid >> 7, k = gid & 127;
  const float* xp = x + n * 7;
  const float* wp = W + k * 7;
  float acc = b[k];
#pragma unroll
  for (int i = 0; i < 7; ++i) acc += xp[i] * wp[i];
  h[gid] = acc;
}

// ---------------- CSR build ----------------
__global__ void hist_kernel(const int* __restrict__ dst, int* __restrict__ cnt) {
  int e = blockIdx.x * blockDim.x + threadIdx.x;
  if (e < NE) atomicAdd(&cnt[dst[e]], 1);
}

// stage 1: per-block sums of cnt
__global__ void partial_kernel(const int* __restrict__ cnt, int* __restrict__ blocksum) {
  __shared__ int red[4];
  int t = threadIdx.x;
  int idx = blockIdx.x * 256 + t;
  int v = idx < NN ? cnt[idx] : 0;
#pragma unroll
  for (int off = 32; off > 0; off >>= 1) v += __shfl_xor(v, off, 64);
  if ((t & 63) == 0) red[t >> 6] = v;
  __syncthreads();
  if (t == 0) blocksum[blockIdx.x] = red[0] + red[1] + red[2] + red[3];
}

// stage 2: exclusive scan of the 157 block sums (single tiny block)
__global__ void scan_small_kernel(const int* __restrict__ blocksum, int* __restrict__ blockoff,
                                  int* __restrict__ row_ptr) {
  __shared__ int sh[256];
  int t = threadIdx.x;
  int v = t < NBLK ? blocksum[t] : 0;
  sh[t] = v;
  __syncthreads();
  for (int off = 1; off < 256; off <<= 1) {
    int u = (t >= off) ? sh[t - off] : 0;
    __syncthreads();
    sh[t] += u;
    __syncthreads();
  }
  if (t < NBLK) blockoff[t] = sh[t] - v;
  if (t == 255) row_ptr[NN] = sh[255];
}

// stage 3: per-block exclusive scan + block offset -> row_ptr
__global__ void rowptr_kernel(const int* __restrict__ cnt, const int* __restrict__ blockoff,
                              int* __restrict__ row_ptr) {
  __shared__ int sh[256];
  int t = threadIdx.x;
  int idx = blockIdx.x * 256 + t;
  int v = idx < NN ? cnt[idx] : 0;
  sh[t] = v;
  __syncthreads();
  for (int off = 1; off < 256; off <<= 1) {
    int u = (t >= off) ? sh[t - off] : 0;
    __syncthreads();
    sh[t] += u;
    __syncthreads();
  }
  if (idx < NN) row_ptr[idx] = blockoff[blockIdx.x] + sh[t] - v;
}

__global__ void scatter_kernel(const int* __restrict__ src, const int* __restrict__ dst,
                               const float* __restrict__ dist,
                               const int* __restrict__ row_ptr, int* __restrict__ fill,
                               int* __restrict__ csr_src, float* __restrict__ csr_w) {
  int e = blockIdx.x * blockDim.x + threadIdx.x;
  if (e >= NE) return;
  int d = dst[e];
  int pos = row_ptr[d] + atomicAdd(&fill[d], 1);
  csr_src[pos] = src[e];
  float dd = dist[e] + 1e-6f;
  csr_w[pos] = 1.0f / (dd * dd);
}

__global__ void wsum_kernel(const int* __restrict__ row_ptr, const float* __restrict__ csr_w,
                            float* __restrict__ wsum) {
  int n = blockIdx.x * blockDim.x + threadIdx.x;
  if (n >= NN) return;
  int s = row_ptr[n], e = row_ptr[n + 1];
  float acc = 0.f;
  for (int i = s; i < e; ++i) acc += csr_w[i];
  wsum[n] = acc;
}

// ---------------- per-layer: aggregate (wave per node) ----------------
// Chunked CSR preload: one per-lane vector load grabs up to 64 edges' (src, w),
// then __shfl broadcasts each edge -> inner loop is pure independent h-row
// gathers the compiler can pipeline (no load->address dependence).
__global__ void aggregate_kernel(const float* __restrict__ h, const int* __restrict__ row_ptr,
                                 const int* __restrict__ csr_src, const float* __restrict__ csr_w,
                                 float* __restrict__ agg) {
  int wid = (blockIdx.x * blockDim.x + threadIdx.x) >> 6;
  int lane = threadIdx.x & 63;
  if (wid >= NN) return;
  int s = row_ptr[wid], e = row_ptr[wid + 1];
  float ax = 0.f, ay = 0.f;
  for (int base = s; base < e; base += 64) {
    int m = e - base;
    if (m > 64) m = 64;
    int idx = base + (lane < m ? lane : m - 1);  // clamp keeps csr loads in-bounds
    int sn_v = csr_src[idx];
    float w_v = csr_w[idx];
    for (int j = 0; j < m; ++j) {
      int sn = __shfl(sn_v, j, 64);
      float w = __shfl(w_v, j, 64);
      float2 hv = *reinterpret_cast<const float2*>(h + sn * HID + lane * 2);
      ax += w * hv.x;
      ay += w * hv.y;
    }
  }
  float2 r = {ax, ay};
  *reinterpret_cast<float2*>(agg + wid * HID + lane * 2) = r;
}

// ---------------- per-layer: h = relu(agg @ W^T + b * wsum) ----------------
__global__ void __launch_bounds__(256) linear_kernel(const float* __restrict__ agg,
                                                     const float* __restrict__ wsum,
                                                     const float* __restrict__ W,
                                                     const float* __restrict__ b,
                                                     float* __restrict__ h) {
  __shared__ float sA[16][HID];
  int t = threadIdx.x;
  int node0 = blockIdx.x * 16;
#pragma unroll
  for (int p = 0; p < 8; ++p) {
    int idx = p * 256 + t;
    int n = idx >> 7, j = idx & 127;
    sA[n][j] = agg[(node0 + n) * HID + j];
  }
  __syncthreads();
  int k = t & 127;
  int ng = (t >> 7) * 8;  // 0 or 8
  float acc[8] = {0.f, 0.f, 0.f, 0.f, 0.f, 0.f, 0.f, 0.f};
  const float* Wk = W + k * HID;
  for (int j = 0; j < HID; j += 4) {
    float4 w4 = *reinterpret_cast<const float4*>(Wk + j);
#pragma unroll
    for (int i = 0; i < 8; ++i) {
      float4 a4 = *reinterpret_cast<const float4*>(&sA[ng + i][j]);
      acc[i] += w4.x * a4.x + w4.y * a4.y + w4.z * a4.z + w4.w * a4.w;
    }
  }
  float bk = b[k];
#pragma unroll
  for (int i = 0; i < 8; ++i) {
    int n = node0 + ng + i;
    float v = acc[i] + bk * wsum[n];
    h[n * HID + k] = fmaxf(v, 0.f);
  }
}

// ---------------- cluster softmax head (wave per node) ----------------
__global__ void cluster_kernel(const float* __restrict__ h, const float* __restrict__ cW,
                               const float* __restrict__ cb, float* __restrict__ out) {
  int wid = (blockIdx.x * blockDim.x + threadIdx.x) >> 6;
  int lane = threadIdx.x & 63;
  if (wid >= NN) return;
  float h0 = h[wid * HID + lane];
  float h1 = h[wid * HID + 64 + lane];
  float logit[3];
#pragma unroll
  for (int c = 0; c < 3; ++c) {
    float p = h0 * cW[c * HID + lane] + h1 * cW[c * HID + 64 + lane];
#pragma unroll
    for (int off = 32; off > 0; off >>= 1) p += __shfl_xor(p, off, 64);
    logit[c] = p + cb[c];
  }
  if (lane == 0) {
    float m = fmaxf(logit[0], fmaxf(logit[1], logit[2]));
    float e0 = expf(logit[0] - m), e1 = expf(logit[1] - m), e2 = expf(logit[2] - m);
    float inv = 1.0f / (e0 + e1 + e2);
    out[wid * 3 + 0] = e0 * inv;
    out[wid * 3 + 1] = e1 * inv;
    out[wid * 3 + 2] = e2 * inv;
  }
}

// ---------------- energy head ----------------
__global__ void colsum_kernel(const float* __restrict__ h, float* __restrict__ colsum) {
  int t = threadIdx.x;  // 0..127 (one column each)
  int base = blockIdx.x * 256;
  int end = base + 256 < NN ? base + 256 : NN;
  float acc = 0.f;
  for (int n = base; n < end; ++n) acc += h[n * HID + t];
  atomicAdd(&colsum[t], acc);
}

__global__ void energy_kernel(const float* __restrict__ colsum, const float* __restrict__ eW,
                              const float* __restrict__ eb, float* __restrict__ out) {
  __shared__ float red[2];
  int t = threadIdx.x;  // 128 threads
  float v = colsum[t] * (1.0f / NN) * eW[t];
#pragma unroll
  for (int off = 32; off > 0; off >>= 1) v += __shfl_xor(v, off, 64);
  if ((t & 63) == 0) red[t >> 6] = v;
  __syncthreads();
  if (t == 0) {
    float e = red[0] + red[1] + eb[0];
    out[NN * 3] = e;
    out[NN * 3 + 1] = (e < -1.0f) ? 1.0f : 0.0f;
  }
}

extern "C" void kernel_launch(void* const* d_in, const int* in_sizes, int n_in,
                              void* d_out, int out_size, void* d_ws, size_t ws_size,
                              hipStream_t stream) {
  const float* x    = (const float*)d_in[0];
  const int*   ei   = (const int*)d_in[1];
  const float* dist = (const float*)d_in[2];
  const float* encW = (const float*)d_in[3];
  const float* encb = (const float*)d_in[4];
  const float* convW = (const float*)d_in[5];
  const float* convb = (const float*)d_in[6];
  const float* cW   = (const float*)d_in[7];
  const float* cb   = (const float*)d_in[8];
  const float* eW   = (const float*)d_in[9];
  const float* eb   = (const float*)d_in[10];
  float* out = (float*)d_out;

  // workspace layout (bytes)
  char* ws = (char*)d_ws;
  float* h       = (float*)(ws + 0);           // 20,480,000
  float* agg     = (float*)(ws + 20480000);    // 20,480,000
  int*   csr_src = (int*)  (ws + 40960000);    //  2,560,000
  float* csr_w   = (float*)(ws + 43520000);    //  2,560,000
  int*   row_ptr = (int*)  (ws + 46080000);    //    160,004 (padded to 160,064)
  int*   cnt     = (int*)  (ws + 46240064);    //    160,000
  int*   fill    = (int*)  (ws + 46400064);    //    160,000
  float* wsum    = (float*)(ws + 46560064);    //    160,000
  float* colsum  = (float*)(ws + 46720064);    //        512
  if (ws_size < (size_t)46720576) return;  // insufficient scratch — fail visibly

  // agg is unused until the first aggregate_kernel -> carve scan scratch from it
  int* blocksum = (int*)agg;          // NBLK ints
  int* blockoff = (int*)agg + 512;    // NBLK ints

  const int* srcI = ei;
  const int* dstI = ei + NE;

  // zero cnt + fill (contiguous) and colsum
  hipMemsetAsync(cnt, 0, 320000, stream);
  hipMemsetAsync(colsum, 0, 512, stream);

  encoder_kernel<<<(NN * HID + 255) / 256, 256, 0, stream>>>(x, encW, encb, h);

  hist_kernel<<<(NE + 255) / 256, 256, 0, stream>>>(dstI, cnt);
  partial_kernel<<<NBLK, 256, 0, stream>>>(cnt, blocksum);
  scan_small_kernel<<<1, 256, 0, stream>>>(blocksum, blockoff, row_ptr);
  rowptr_kernel<<<NBLK, 256, 0, stream>>>(cnt, blockoff, row_ptr);
  scatter_kernel<<<(NE + 255) / 256, 256, 0, stream>>>(srcI, dstI, dist, row_ptr, fill,
                                                       csr_src, csr_w);
  wsum_kernel<<<(NN + 255) / 256, 256, 0, stream>>>(row_ptr, csr_w, wsum);

  for (int l = 0; l < NL; ++l) {
    aggregate_kernel<<<(NN * 64 + 255) / 256, 256, 0, stream>>>(h, row_ptr, csr_src, csr_w, agg);
    linear_kernel<<<NN / 16, 256, 0, stream>>>(agg, wsum, convW + (size_t)l * HID * HID,
                                               convb + (size_t)l * HID, h);
  }

  cluster_kernel<<<(NN * 64 + 255) / 256, 256, 0, stream>>>(h, cW, cb, out);
  colsum_kernel<<<(NN + 255) / 256, 128, 0, stream>>>(h, colsum);
  energy_kernel<<<1, 128, 0, stream>>>(colsum, eW, eb, out);
}

// Round 4
// 632.241 us; speedup vs baseline: 1.3304x; 1.0823x over previous
//
#include <hip/hip_runtime.h>

#define NN 40000
#define NE 640000
#define HID 128
#define NL 5
#define NBLK 157  // ceil(40000/256)

// ---------------- encoder: h[n][k] = x[n][:7] . encW[k][:7] + encb[k] ----------------
__global__ void encoder_kernel(const float* __restrict__ x, const float* __restrict__ W,
                               const float* __restrict__ b, float* __restrict__ h) {
  int gid = blockIdx.x * blockDim.x + threadIdx.x;
  if (gid >= NN * HID) return;
  int n = gid >> 7, k = gid & 127;
  const float* xp = x + n * 7;
  const float* wp = W + k * 7;
  float acc = b[k];
#pragma unroll
  for (int i = 0; i < 7; ++i) acc += xp[i] * wp[i];
  h[gid] = acc;
}

// ---------------- CSR build ----------------
__global__ void hist_kernel(const int* __restrict__ dst, int* __restrict__ cnt) {
  int e = blockIdx.x * blockDim.x + threadIdx.x;
  if (e < NE) atomicAdd(&cnt[dst[e]], 1);
}

// stage 1: per-block sums of cnt
__global__ void partial_kernel(const int* __restrict__ cnt, int* __restrict__ blocksum) {
  __shared__ int red[4];
  int t = threadIdx.x;
  int idx = blockIdx.x * 256 + t;
  int v = idx < NN ? cnt[idx] : 0;
#pragma unroll
  for (int off = 32; off > 0; off >>= 1) v += __shfl_xor(v, off, 64);
  if ((t & 63) == 0) red[t >> 6] = v;
  __syncthreads();
  if (t == 0) blocksum[blockIdx.x] = red[0] + red[1] + red[2] + red[3];
}

// stage 2: exclusive scan of the 157 block sums (single tiny block)
__global__ void scan_small_kernel(const int* __restrict__ blocksum, int* __restrict__ blockoff,
                                  int* __restrict__ row_ptr) {
  __shared__ int sh[256];
  int t = threadIdx.x;
  int v = t < NBLK ? blocksum[t] : 0;
  sh[t] = v;
  __syncthreads();
  for (int off = 1; off < 256; off <<= 1) {
    int u = (t >= off) ? sh[t - off] : 0;
    __syncthreads();
    sh[t] += u;
    __syncthreads();
  }
  if (t < NBLK) blockoff[t] = sh[t] - v;
  if (t == 255) row_ptr[NN] = sh[255];
}

// stage 3: per-block exclusive scan + block offset -> row_ptr
__global__ void rowptr_kernel(const int* __restrict__ cnt, const int* __restrict__ blockoff,
                              int* __restrict__ row_ptr) {
  __shared__ int sh[256];
  int t = threadIdx.x;
  int idx = blockIdx.x * 256 + t;
  int v = idx < NN ? cnt[idx] : 0;
  sh[t] = v;
  __syncthreads();
  for (int off = 1; off < 256; off <<= 1) {
    int u = (t >= off) ? sh[t - off] : 0;
    __syncthreads();
    sh[t] += u;
    __syncthreads();
  }
  if (idx < NN) row_ptr[idx] = blockoff[blockIdx.x] + sh[t] - v;
}

__global__ void scatter_kernel(const int* __restrict__ src, const int* __restrict__ dst,
                               const float* __restrict__ dist,
                               const int* __restrict__ row_ptr, int* __restrict__ fill,
                               int* __restrict__ csr_src, float* __restrict__ csr_w) {
  int e = blockIdx.x * blockDim.x + threadIdx.x;
  if (e >= NE) return;
  int d = dst[e];
  int pos = row_ptr[d] + atomicAdd(&fill[d], 1);
  csr_src[pos] = src[e];
  float dd = dist[e] + 1e-6f;
  csr_w[pos] = 1.0f / (dd * dd);
}

__global__ void wsum_kernel(const int* __restrict__ row_ptr, const float* __restrict__ csr_w,
                            float* __restrict__ wsum) {
  int n = blockIdx.x * blockDim.x + threadIdx.x;
  if (n >= NN) return;
  int s = row_ptr[n], e = row_ptr[n + 1];
  float acc = 0.f;
  for (int i = s; i < e; ++i) acc += csr_w[i];
  wsum[n] = acc;
}

// ---------------- per-layer: aggregate (wave per node) ----------------
// Chunked CSR preload: one per-lane vector load grabs up to 64 edges' (src, w),
// then __shfl broadcasts each edge -> inner loop is pure independent h-row
// gathers the compiler can pipeline (no load->address dependence).
__global__ void aggregate_kernel(const float* __restrict__ h, const int* __restrict__ row_ptr,
                                 const int* __restrict__ csr_src, const float* __restrict__ csr_w,
                                 float* __restrict__ agg) {
  int wid = (blockIdx.x * blockDim.x + threadIdx.x) >> 6;
  int lane = threadIdx.x & 63;
  if (wid >= NN) return;
  int s = row_ptr[wid], e = row_ptr[wid + 1];
  float ax = 0.f, ay = 0.f;
  for (int base = s; base < e; base += 64) {
    int m = e - base;
    if (m > 64) m = 64;
    int idx = base + (lane < m ? lane : m - 1);  // clamp keeps csr loads in-bounds
    int sn_v = csr_src[idx];
    float w_v = csr_w[idx];
    for (int j = 0; j < m; ++j) {
      int sn = __shfl(sn_v, j, 64);
      float w = __shfl(w_v, j, 64);
      float2 hv = *reinterpret_cast<const float2*>(h + sn * HID + lane * 2);
      ax += w * hv.x;
      ay += w * hv.y;
    }
  }
  float2 r = {ax, ay};
  *reinterpret_cast<float2*>(agg + wid * HID + lane * 2) = r;
}

// ---------------- per-layer: h = relu(agg @ W^T + b * wsum) ----------------
__global__ void __launch_bounds__(256) linear_kernel(const float* __restrict__ agg,
                                                     const float* __restrict__ wsum,
                                                     const float* __restrict__ W,
                                                     const float* __restrict__ b,
                                                     float* __restrict__ h) {
  __shared__ float sA[16][HID];
  int t = threadIdx.x;
  int node0 = blockIdx.x * 16;
#pragma unroll
  for (int p = 0; p < 8; ++p) {
    int idx = p * 256 + t;
    int n = idx >> 7, j = idx & 127;
    sA[n][j] = agg[(node0 + n) * HID + j];
  }
  __syncthreads();
  int k = t & 127;
  int ng = (t >> 7) * 8;  // 0 or 8
  float acc[8] = {0.f, 0.f, 0.f, 0.f, 0.f, 0.f, 0.f, 0.f};
  const float* Wk = W + k * HID;
  for (int j = 0; j < HID; j += 4) {
    float4 w4 = *reinterpret_cast<const float4*>(Wk + j);
#pragma unroll
    for (int i = 0; i < 8; ++i) {
      float4 a4 = *reinterpret_cast<const float4*>(&sA[ng + i][j]);
      acc[i] += w4.x * a4.x + w4.y * a4.y + w4.z * a4.z + w4.w * a4.w;
    }
  }
  float bk = b[k];
#pragma unroll
  for (int i = 0; i < 8; ++i) {
    int n = node0 + ng + i;
    float v = acc[i] + bk * wsum[n];
    h[n * HID + k] = fmaxf(v, 0.f);
  }
}

// ---------------- cluster softmax head (wave per node) ----------------
__global__ void cluster_kernel(const float* __restrict__ h, const float* __restrict__ cW,
                               const float* __restrict__ cb, float* __restrict__ out) {
  int wid = (blockIdx.x * blockDim.x + threadIdx.x) >> 6;
  int lane = threadIdx.x & 63;
  if (wid >= NN) return;
  float h0 = h[wid * HID + lane];
  float h1 = h[wid * HID + 64 + lane];
  float logit[3];
#pragma unroll
  for (int c = 0; c < 3; ++c) {
    float p = h0 * cW[c * HID + lane] + h1 * cW[c * HID + 64 + lane];
#pragma unroll
    for (int off = 32; off > 0; off >>= 1) p += __shfl_xor(p, off, 64);
    logit[c] = p + cb[c];
  }
  if (lane == 0) {
    float m = fmaxf(logit[0], fmaxf(logit[1], logit[2]));
    float e0 = expf(logit[0] - m), e1 = expf(logit[1] - m), e2 = expf(logit[2] - m);
    float inv = 1.0f / (e0 + e1 + e2);
    out[wid * 3 + 0] = e0 * inv;
    out[wid * 3 + 1] = e1 * inv;
    out[wid * 3 + 2] = e2 * inv;
  }
}

// ---------------- energy head: two-stage column reduction ----------------
// stage 1: 1024 blocks x 256 threads; 2 row-lanes x 128 cols per block.
// partial[2048][128] (carved from agg, dead after the last linear layer).
__global__ void colsum_part_kernel(const float* __restrict__ h, float* __restrict__ partial) {
  int t = threadIdx.x;
  int col = t & 127;
  int lane_id = blockIdx.x * 2 + (t >> 7);  // [0, 2048)
  float acc = 0.f;
  for (int r = lane_id; r < NN; r += 2048) acc += h[r * HID + col];
  partial[lane_id * HID + col] = acc;
}

// stage 2 (fused energy): one 1024-thread block reduces 2048 partials/col,
// then computes energy = mean . eW + eb and stable flag.
__global__ void energy_final_kernel(const float* __restrict__ partial,
                                    const float* __restrict__ eW, const float* __restrict__ eb,
                                    float* __restrict__ out) {
  __shared__ float sh[8][HID];
  __shared__ float red[2];
  int t = threadIdx.x;
  int col = t & 127;
  int slot = t >> 7;  // 0..7
  float acc = 0.f;
  for (int i = 0; i < 256; ++i) acc += partial[(slot + 8 * i) * HID + col];
  sh[slot][col] = acc;
  __syncthreads();
  if (t < 128) {
    float s = 0.f;
#pragma unroll
    for (int j = 0; j < 8; ++j) s += sh[j][t];
    float v = s * (1.0f / NN) * eW[t];
#pragma unroll
    for (int off = 32; off > 0; off >>= 1) v += __shfl_xor(v, off, 64);
    if ((t & 63) == 0) red[t >> 6] = v;
  }
  __syncthreads();
  if (t == 0) {
    float e = red[0] + red[1] + eb[0];
    out[NN * 3] = e;
    out[NN * 3 + 1] = (e < -1.0f) ? 1.0f : 0.0f;
  }
}

extern "C" void kernel_launch(void* const* d_in, const int* in_sizes, int n_in,
                              void* d_out, int out_size, void* d_ws, size_t ws_size,
                              hipStream_t stream) {
  const float* x    = (const float*)d_in[0];
  const int*   ei   = (const int*)d_in[1];
  const float* dist = (const float*)d_in[2];
  const float* encW = (const float*)d_in[3];
  const float* encb = (const float*)d_in[4];
  const float* convW = (const float*)d_in[5];
  const float* convb = (const float*)d_in[6];
  const float* cW   = (const float*)d_in[7];
  const float* cb   = (const float*)d_in[8];
  const float* eW   = (const float*)d_in[9];
  const float* eb   = (const float*)d_in[10];
  float* out = (float*)d_out;

  // workspace layout (bytes)
  char* ws = (char*)d_ws;
  float* h       = (float*)(ws + 0);           // 20,480,000
  float* agg     = (float*)(ws + 20480000);    // 20,480,000
  int*   csr_src = (int*)  (ws + 40960000);    //  2,560,000
  float* csr_w   = (float*)(ws + 43520000);    //  2,560,000
  int*   row_ptr = (int*)  (ws + 46080000);    //    160,004 (padded to 160,064)
  int*   cnt     = (int*)  (ws + 46240064);    //    160,000
  int*   fill    = (int*)  (ws + 46400064);    //    160,000
  float* wsum    = (float*)(ws + 46560064);    //    160,000
  if (ws_size < (size_t)46720576) return;  // insufficient scratch — fail visibly

  // agg is unused until the first aggregate_kernel -> carve scan scratch from it;
  // agg is dead again after the last linear_kernel -> reuse for column partials.
  int*   blocksum = (int*)agg;          // NBLK ints
  int*   blockoff = (int*)agg + 512;    // NBLK ints
  float* partial  = agg;                // 2048*128 floats = 1 MB

  const int* srcI = ei;
  const int* dstI = ei + NE;

  // zero cnt + fill (contiguous)
  hipMemsetAsync(cnt, 0, 320000, stream);

  encoder_kernel<<<(NN * HID + 255) / 256, 256, 0, stream>>>(x, encW, encb, h);

  hist_kernel<<<(NE + 255) / 256, 256, 0, stream>>>(dstI, cnt);
  partial_kernel<<<NBLK, 256, 0, stream>>>(cnt, blocksum);
  scan_small_kernel<<<1, 256, 0, stream>>>(blocksum, blockoff, row_ptr);
  rowptr_kernel<<<NBLK, 256, 0, stream>>>(cnt, blockoff, row_ptr);
  scatter_kernel<<<(NE + 255) / 256, 256, 0, stream>>>(srcI, dstI, dist, row_ptr, fill,
                                                       csr_src, csr_w);
  wsum_kernel<<<(NN + 255) / 256, 256, 0, stream>>>(row_ptr, csr_w, wsum);

  for (int l = 0; l < NL; ++l) {
    aggregate_kernel<<<(NN * 64 + 255) / 256, 256, 0, stream>>>(h, row_ptr, csr_src, csr_w, agg);
    linear_kernel<<<NN / 16, 256, 0, stream>>>(agg, wsum, convW + (size_t)l * HID * HID,
                                               convb + (size_t)l * HID, h);
  }

  cluster_kernel<<<(NN * 64 + 255) / 256, 256, 0, stream>>>(h, cW, cb, out);
  colsum_part_kernel<<<1024, 256, 0, stream>>>(h, partial);
  energy_final_kernel<<<1, 1024, 0, stream>>>(partial, eW, eb, out);
}

// Round 5
// 530.259 us; speedup vs baseline: 1.5863x; 1.1923x over previous
//
#include <hip/hip_runtime.h>

#define NN 40000
#define NE 640000
#define HID 128
#define NL 5
#define NBLK 157  // ceil(40000/256)

typedef __attribute__((ext_vector_type(8))) short bf16x8;
typedef __attribute__((ext_vector_type(4))) float f32x4;

static __device__ __forceinline__ unsigned short f32_to_bf16_rne(float f) {
  unsigned int u = __float_as_uint(f);
  unsigned int lsb = (u >> 16) & 1u;
  u += 0x7fffu + lsb;
  return (unsigned short)(u >> 16);
}
static __device__ __forceinline__ float bf16_to_f32(unsigned short s) {
  return __uint_as_float(((unsigned int)s) << 16);
}

// ---------------- encoder: h[n][k] = x[n][:7] . encW[k][:7] + encb[k] ----------------
__global__ void encoder_kernel(const float* __restrict__ x, const float* __restrict__ W,
                               const float* __restrict__ b, float* __restrict__ h) {
  int gid = blockIdx.x * blockDim.x + threadIdx.x;
  if (gid >= NN * HID) return;
  int n = gid >> 7, k = gid & 127;
  const float* xp = x + n * 7;
  const float* wp = W + k * 7;
  float acc = b[k];
#pragma unroll
  for (int i = 0; i < 7; ++i) acc += xp[i] * wp[i];
  h[gid] = acc;
}

// ---------------- split all 5 conv_W into bf16 hi/lo planes ----------------
__global__ void wconv_kernel(const float* __restrict__ W, unsigned short* __restrict__ whi,
                             unsigned short* __restrict__ wlo) {
  int i = blockIdx.x * 256 + threadIdx.x;
  if (i >= NL * HID * HID) return;
  float w = W[i];
  unsigned short hi = f32_to_bf16_rne(w);
  unsigned short lo = f32_to_bf16_rne(w - bf16_to_f32(hi));
  whi[i] = hi;
  wlo[i] = lo;
}

// ---------------- CSR build ----------------
__global__ void hist_kernel(const int* __restrict__ dst, int* __restrict__ cnt) {
  int e = blockIdx.x * blockDim.x + threadIdx.x;
  if (e < NE) atomicAdd(&cnt[dst[e]], 1);
}

__global__ void partial_kernel(const int* __restrict__ cnt, int* __restrict__ blocksum) {
  __shared__ int red[4];
  int t = threadIdx.x;
  int idx = blockIdx.x * 256 + t;
  int v = idx < NN ? cnt[idx] : 0;
#pragma unroll
  for (int off = 32; off > 0; off >>= 1) v += __shfl_xor(v, off, 64);
  if ((t & 63) == 0) red[t >> 6] = v;
  __syncthreads();
  if (t == 0) blocksum[blockIdx.x] = red[0] + red[1] + red[2] + red[3];
}

__global__ void scan_small_kernel(const int* __restrict__ blocksum, int* __restrict__ blockoff,
                                  int* __restrict__ row_ptr) {
  __shared__ int sh[256];
  int t = threadIdx.x;
  int v = t < NBLK ? blocksum[t] : 0;
  sh[t] = v;
  __syncthreads();
  for (int off = 1; off < 256; off <<= 1) {
    int u = (t >= off) ? sh[t - off] : 0;
    __syncthreads();
    sh[t] += u;
    __syncthreads();
  }
  if (t < NBLK) blockoff[t] = sh[t] - v;
  if (t == 255) row_ptr[NN] = sh[255];
}

__global__ void rowptr_kernel(const int* __restrict__ cnt, const int* __restrict__ blockoff,
                              int* __restrict__ row_ptr) {
  __shared__ int sh[256];
  int t = threadIdx.x;
  int idx = blockIdx.x * 256 + t;
  int v = idx < NN ? cnt[idx] : 0;
  sh[t] = v;
  __syncthreads();
  for (int off = 1; off < 256; off <<= 1) {
    int u = (t >= off) ? sh[t - off] : 0;
    __syncthreads();
    sh[t] += u;
    __syncthreads();
  }
  if (idx < NN) row_ptr[idx] = blockoff[blockIdx.x] + sh[t] - v;
}

__global__ void scatter_kernel(const int* __restrict__ src, const int* __restrict__ dst,
                               const float* __restrict__ dist,
                               const int* __restrict__ row_ptr, int* __restrict__ fill,
                               int* __restrict__ csr_src, float* __restrict__ csr_w) {
  int e = blockIdx.x * blockDim.x + threadIdx.x;
  if (e >= NE) return;
  int d = dst[e];
  int pos = row_ptr[d] + atomicAdd(&fill[d], 1);
  csr_src[pos] = src[e];
  float dd = dist[e] + 1e-6f;
  csr_w[pos] = 1.0f / (dd * dd);
}

__global__ void wsum_kernel(const int* __restrict__ row_ptr, const float* __restrict__ csr_w,
                            float* __restrict__ wsum) {
  int n = blockIdx.x * blockDim.x + threadIdx.x;
  if (n >= NN) return;
  int s = row_ptr[n], e = row_ptr[n + 1];
  float acc = 0.f;
  for (int i = s; i < e; ++i) acc += csr_w[i];
  wsum[n] = acc;
}

// ---------------- per-layer: aggregate (wave per node), emits bf16 hi/lo ----------------
__global__ void aggregate_kernel(const float* __restrict__ h, const int* __restrict__ row_ptr,
                                 const int* __restrict__ csr_src, const float* __restrict__ csr_w,
                                 unsigned short* __restrict__ aggh,
                                 unsigned short* __restrict__ aggl) {
  int wid = (blockIdx.x * blockDim.x + threadIdx.x) >> 6;
  int lane = threadIdx.x & 63;
  if (wid >= NN) return;
  int s = row_ptr[wid], e = row_ptr[wid + 1];
  float ax = 0.f, ay = 0.f;
  for (int base = s; base < e; base += 64) {
    int m = e - base;
    if (m > 64) m = 64;
    int idx = base + (lane < m ? lane : m - 1);  // clamp keeps csr loads in-bounds
    int sn_v = csr_src[idx];
    float w_v = csr_w[idx];
    for (int j = 0; j < m; ++j) {
      int sn = __shfl(sn_v, j, 64);
      float w = __shfl(w_v, j, 64);
      float2 hv = *reinterpret_cast<const float2*>(h + sn * HID + lane * 2);
      ax += w * hv.x;
      ay += w * hv.y;
    }
  }
  unsigned short hx = f32_to_bf16_rne(ax);
  unsigned short lx = f32_to_bf16_rne(ax - bf16_to_f32(hx));
  unsigned short hy = f32_to_bf16_rne(ay);
  unsigned short ly = f32_to_bf16_rne(ay - bf16_to_f32(hy));
  ushort2 hv = {hx, hy}, lv = {lx, ly};
  *reinterpret_cast<ushort2*>(aggh + wid * HID + lane * 2) = hv;
  *reinterpret_cast<ushort2*>(aggl + wid * HID + lane * 2) = lv;
}

// ---------------- per-layer: h = relu(agg @ W^T + b * wsum) via split-bf16 MFMA ----------
// wave = 16 nodes x 128 outputs, K=128. a*w ~= ah*wh + ah*wl + al*wh (fp32 acc).
// A-frag: lane holds row (lane&15), k-chunk (lane>>4)*8. B-frag: col (lane&15), same k.
// D: col(kout)=lane&15, row(node)=(lane>>4)*4+reg  [guide §3, m89-verified].
__global__ void __launch_bounds__(256) mfma_linear_kernel(
    const unsigned short* __restrict__ aggh, const unsigned short* __restrict__ aggl,
    const unsigned short* __restrict__ whi, const unsigned short* __restrict__ wlo,
    const float* __restrict__ wsum, const float* __restrict__ b, float* __restrict__ h) {
  int wave = threadIdx.x >> 6;
  int lane = threadIdx.x & 63;
  int node0 = blockIdx.x * 64 + wave * 16;
  int mrow = lane & 15;
  int kc = (lane >> 4) * 8;

  const unsigned short* pah = aggh + (node0 + mrow) * HID;
  const unsigned short* pal = aggl + (node0 + mrow) * HID;

  f32x4 acc[8];
#pragma unroll
  for (int t = 0; t < 8; ++t) acc[t] = (f32x4){0.f, 0.f, 0.f, 0.f};

#pragma unroll
  for (int s = 0; s < 4; ++s) {
    int joff = s * 32 + kc;
    bf16x8 ah = *reinterpret_cast<const bf16x8*>(pah + joff);
    bf16x8 al = *reinterpret_cast<const bf16x8*>(pal + joff);
#pragma unroll
    for (int t = 0; t < 8; ++t) {
      bf16x8 bh = *reinterpret_cast<const bf16x8*>(whi + (t * 16 + mrow) * HID + joff);
      bf16x8 bl = *reinterpret_cast<const bf16x8*>(wlo + (t * 16 + mrow) * HID + joff);
      acc[t] = __builtin_amdgcn_mfma_f32_16x16x32_bf16(ah, bh, acc[t], 0, 0, 0);
      acc[t] = __builtin_amdgcn_mfma_f32_16x16x32_bf16(ah, bl, acc[t], 0, 0, 0);
      acc[t] = __builtin_amdgcn_mfma_f32_16x16x32_bf16(al, bh, acc[t], 0, 0, 0);
    }
  }

  int nodeBase = node0 + (lane >> 4) * 4;
  float ws4[4];
#pragma unroll
  for (int r = 0; r < 4; ++r) ws4[r] = wsum[nodeBase + r];
#pragma unroll
  for (int t = 0; t < 8; ++t) {
    int kout = t * 16 + mrow;
    float bk = b[kout];
#pragma unroll
    for (int r = 0; r < 4; ++r) {
      float v = acc[t][r] + bk * ws4[r];
      h[(nodeBase + r) * HID + kout] = fmaxf(v, 0.f);
    }
  }
}

// ---------------- cluster softmax head (wave per node) ----------------
__global__ void cluster_kernel(const float* __restrict__ h, const float* __restrict__ cW,
                               const float* __restrict__ cb, float* __restrict__ out) {
  int wid = (blockIdx.x * blockDim.x + threadIdx.x) >> 6;
  int lane = threadIdx.x & 63;
  if (wid >= NN) return;
  float h0 = h[wid * HID + lane];
  float h1 = h[wid * HID + 64 + lane];
  float logit[3];
#pragma unroll
  for (int c = 0; c < 3; ++c) {
    float p = h0 * cW[c * HID + lane] + h1 * cW[c * HID + 64 + lane];
#pragma unroll
    for (int off = 32; off > 0; off >>= 1) p += __shfl_xor(p, off, 64);
    logit[c] = p + cb[c];
  }
  if (lane == 0) {
    float m = fmaxf(logit[0], fmaxf(logit[1], logit[2]));
    float e0 = expf(logit[0] - m), e1 = expf(logit[1] - m), e2 = expf(logit[2] - m);
    float inv = 1.0f / (e0 + e1 + e2);
    out[wid * 3 + 0] = e0 * inv;
    out[wid * 3 + 1] = e1 * inv;
    out[wid * 3 + 2] = e2 * inv;
  }
}

// ---------------- energy head: two-stage column reduction ----------------
__global__ void colsum_part_kernel(const float* __restrict__ h, float* __restrict__ partial) {
  int t = threadIdx.x;
  int col = t & 127;
  int lane_id = blockIdx.x * 2 + (t >> 7);  // [0, 2048)
  float acc = 0.f;
  for (int r = lane_id; r < NN; r += 2048) acc += h[r * HID + col];
  partial[lane_id * HID + col] = acc;
}

__global__ void energy_final_kernel(const float* __restrict__ partial,
                                    const float* __restrict__ eW, const float* __restrict__ eb,
                                    float* __restrict__ out) {
  __shared__ float sh[8][HID];
  __shared__ float red[2];
  int t = threadIdx.x;
  int col = t & 127;
  int slot = t >> 7;  // 0..7
  float acc = 0.f;
  for (int i = 0; i < 256; ++i) acc += partial[(slot + 8 * i) * HID + col];
  sh[slot][col] = acc;
  __syncthreads();
  if (t < 128) {
    float s = 0.f;
#pragma unroll
    for (int j = 0; j < 8; ++j) s += sh[j][t];
    float v = s * (1.0f / NN) * eW[t];
#pragma unroll
    for (int off = 32; off > 0; off >>= 1) v += __shfl_xor(v, off, 64);
    if ((t & 63) == 0) red[t >> 6] = v;
  }
  __syncthreads();
  if (t == 0) {
    float e = red[0] + red[1] + eb[0];
    out[NN * 3] = e;
    out[NN * 3 + 1] = (e < -1.0f) ? 1.0f : 0.0f;
  }
}

extern "C" void kernel_launch(void* const* d_in, const int* in_sizes, int n_in,
                              void* d_out, int out_size, void* d_ws, size_t ws_size,
                              hipStream_t stream) {
  const float* x    = (const float*)d_in[0];
  const int*   ei   = (const int*)d_in[1];
  const float* dist = (const float*)d_in[2];
  const float* encW = (const float*)d_in[3];
  const float* encb = (const float*)d_in[4];
  const float* convW = (const float*)d_in[5];
  const float* convb = (const float*)d_in[6];
  const float* cW   = (const float*)d_in[7];
  const float* cb   = (const float*)d_in[8];
  const float* eW   = (const float*)d_in[9];
  const float* eb   = (const float*)d_in[10];
  float* out = (float*)d_out;

  // workspace layout (bytes)
  char* ws = (char*)d_ws;
  float*          h       = (float*)         (ws + 0);           // 20,480,000
  unsigned short* aggh    = (unsigned short*)(ws + 20480000);    // 10,240,000
  unsigned short* aggl    = (unsigned short*)(ws + 30720000);    // 10,240,000
  int*            csr_src = (int*)           (ws + 40960000);    //  2,560,000
  float*          csr_w   = (float*)         (ws + 43520000);    //  2,560,000
  int*            row_ptr = (int*)           (ws + 46080000);    //    160,064
  int*            cnt     = (int*)           (ws + 46240064);    //    160,000
  int*            fill    = (int*)           (ws + 46400064);    //    160,000
  float*          wsum    = (float*)         (ws + 46560064);    //    160,000
  unsigned short* whi5    = (unsigned short*)(ws + 46720064);    //    163,840
  unsigned short* wlo5    = (unsigned short*)(ws + 46883904);    //    163,840
  if (ws_size < (size_t)47047744) return;  // insufficient scratch — fail visibly

  // aggh region is dead until the first aggregate -> scan scratch lives there;
  // and dead again after the last mfma_linear -> colsum partials live there.
  int*   blocksum = (int*)aggh;
  int*   blockoff = (int*)aggh + 512;
  float* partial  = (float*)aggh;  // 2048*128 floats = 1 MB

  const int* srcI = ei;
  const int* dstI = ei + NE;

  hipMemsetAsync(cnt, 0, 320000, stream);  // cnt + fill (contiguous)

  encoder_kernel<<<(NN * HID + 255) / 256, 256, 0, stream>>>(x, encW, encb, h);
  wconv_kernel<<<(NL * HID * HID + 255) / 256, 256, 0, stream>>>(convW, whi5, wlo5);

  hist_kernel<<<(NE + 255) / 256, 256, 0, stream>>>(dstI, cnt);
  partial_kernel<<<NBLK, 256, 0, stream>>>(cnt, blocksum);
  scan_small_kernel<<<1, 256, 0, stream>>>(blocksum, blockoff, row_ptr);
  rowptr_kernel<<<NBLK, 256, 0, stream>>>(cnt, blockoff, row_ptr);
  scatter_kernel<<<(NE + 255) / 256, 256, 0, stream>>>(srcI, dstI, dist, row_ptr, fill,
                                                       csr_src, csr_w);
  wsum_kernel<<<(NN + 255) / 256, 256, 0, stream>>>(row_ptr, csr_w, wsum);

  for (int l = 0; l < NL; ++l) {
    aggregate_kernel<<<(NN * 64 + 255) / 256, 256, 0, stream>>>(h, row_ptr, csr_src, csr_w,
                                                                aggh, aggl);
    mfma_linear_kernel<<<NN / 64, 256, 0, stream>>>(aggh, aggl,
                                                    whi5 + (size_t)l * HID * HID,
                                                    wlo5 + (size_t)l * HID * HID,
                                                    wsum, convb + (size_t)l * HID, h);
  }

  cluster_kernel<<<(NN * 64 + 255) / 256, 256, 0, stream>>>(h, cW, cb, out);
  colsum_part_kernel<<<1024, 256, 0, stream>>>(h, partial);
  energy_final_kernel<<<1, 1024, 0, stream>>>(partial, eW, eb, out);
}

// Round 6
// 495.919 us; speedup vs baseline: 1.6961x; 1.0692x over previous
//
#include <hip/hip_runtime.h>
#include <hip/hip_fp16.h>

#define NN 40000
#define NE 640000
#define HID 128
#define NL 5
#define NBLK 157  // ceil(40000/256)

typedef __attribute__((ext_vector_type(8))) short bf16x8;
typedef __attribute__((ext_vector_type(4))) float f32x4;

static __device__ __forceinline__ unsigned short f32_to_bf16_rne(float f) {
  unsigned int u = __float_as_uint(f);
  unsigned int lsb = (u >> 16) & 1u;
  u += 0x7fffu + lsb;
  return (unsigned short)(u >> 16);
}
static __device__ __forceinline__ float bf16_to_f32(unsigned short s) {
  return __uint_as_float(((unsigned int)s) << 16);
}

// ---------------- encoder: h[n][k] = x[n][:7] . encW[k][:7] + encb[k] (fp16 out) ------
__global__ void encoder_kernel(const float* __restrict__ x, const float* __restrict__ W,
                               const float* __restrict__ b, __half* __restrict__ h) {
  int gid = blockIdx.x * blockDim.x + threadIdx.x;
  if (gid >= NN * HID) return;
  int n = gid >> 7, k = gid & 127;
  const float* xp = x + n * 7;
  const float* wp = W + k * 7;
  float acc = b[k];
#pragma unroll
  for (int i = 0; i < 7; ++i) acc += xp[i] * wp[i];
  h[gid] = __float2half(acc);
}

// ---------------- split all 5 conv_W into bf16 hi/lo planes ----------------
__global__ void wconv_kernel(const float* __restrict__ W, unsigned short* __restrict__ whi,
                             unsigned short* __restrict__ wlo) {
  int i = blockIdx.x * 256 + threadIdx.x;
  if (i >= NL * HID * HID) return;
  float w = W[i];
  unsigned short hi = f32_to_bf16_rne(w);
  unsigned short lo = f32_to_bf16_rne(w - bf16_to_f32(hi));
  whi[i] = hi;
  wlo[i] = lo;
}

// ---------------- CSR build ----------------
__global__ void hist_kernel(const int* __restrict__ dst, int* __restrict__ cnt) {
  int e = blockIdx.x * blockDim.x + threadIdx.x;
  if (e < NE) atomicAdd(&cnt[dst[e]], 1);
}

__global__ void partial_kernel(const int* __restrict__ cnt, int* __restrict__ blocksum) {
  __shared__ int red[4];
  int t = threadIdx.x;
  int idx = blockIdx.x * 256 + t;
  int v = idx < NN ? cnt[idx] : 0;
#pragma unroll
  for (int off = 32; off > 0; off >>= 1) v += __shfl_xor(v, off, 64);
  if ((t & 63) == 0) red[t >> 6] = v;
  __syncthreads();
  if (t == 0) blocksum[blockIdx.x] = red[0] + red[1] + red[2] + red[3];
}

__global__ void scan_small_kernel(const int* __restrict__ blocksum, int* __restrict__ blockoff,
                                  int* __restrict__ row_ptr) {
  __shared__ int sh[256];
  int t = threadIdx.x;
  int v = t < NBLK ? blocksum[t] : 0;
  sh[t] = v;
  __syncthreads();
  for (int off = 1; off < 256; off <<= 1) {
    int u = (t >= off) ? sh[t - off] : 0;
    __syncthreads();
    sh[t] += u;
    __syncthreads();
  }
  if (t < NBLK) blockoff[t] = sh[t] - v;
  if (t == 255) row_ptr[NN] = sh[255];
}

__global__ void rowptr_kernel(const int* __restrict__ cnt, const int* __restrict__ blockoff,
                              int* __restrict__ row_ptr) {
  __shared__ int sh[256];
  int t = threadIdx.x;
  int idx = blockIdx.x * 256 + t;
  int v = idx < NN ? cnt[idx] : 0;
  sh[t] = v;
  __syncthreads();
  for (int off = 1; off < 256; off <<= 1) {
    int u = (t >= off) ? sh[t - off] : 0;
    __syncthreads();
    sh[t] += u;
    __syncthreads();
  }
  if (idx < NN) row_ptr[idx] = blockoff[blockIdx.x] + sh[t] - v;
}

__global__ void scatter_kernel(const int* __restrict__ src, const int* __restrict__ dst,
                               const float* __restrict__ dist,
                               const int* __restrict__ row_ptr, int* __restrict__ fill,
                               int* __restrict__ csr_src, float* __restrict__ csr_w) {
  int e = blockIdx.x * blockDim.x + threadIdx.x;
  if (e >= NE) return;
  int d = dst[e];
  int pos = row_ptr[d] + atomicAdd(&fill[d], 1);
  csr_src[pos] = src[e];
  float dd = dist[e] + 1e-6f;
  csr_w[pos] = 1.0f / (dd * dd);
}

__global__ void wsum_kernel(const int* __restrict__ row_ptr, const float* __restrict__ csr_w,
                            float* __restrict__ wsum) {
  int n = blockIdx.x * blockDim.x + threadIdx.x;
  if (n >= NN) return;
  int s = row_ptr[n], e = row_ptr[n + 1];
  float acc = 0.f;
  for (int i = s; i < e; ++i) acc += csr_w[i];
  wsum[n] = acc;
}

// ---------------- per-layer: aggregate (wave per node, fp16 gather) ----------------
// CSR chunk preload (64 edges per vector load), then readlane-broadcast each edge:
// sn/w become SGPRs -> the gather is global_load_dword with scalar base, and all
// iterations' loads are independent (no load->address dependence).
__global__ void aggregate_kernel(const __half* __restrict__ h, const int* __restrict__ row_ptr,
                                 const int* __restrict__ csr_src, const float* __restrict__ csr_w,
                                 unsigned short* __restrict__ aggh,
                                 unsigned short* __restrict__ aggl) {
  int wid = (blockIdx.x * blockDim.x + threadIdx.x) >> 6;
  int lane = threadIdx.x & 63;
  if (wid >= NN) return;
  int s = row_ptr[wid], e = row_ptr[wid + 1];
  float ax = 0.f, ay = 0.f;
  for (int base = s; base < e; base += 64) {
    int m = e - base;
    if (m > 64) m = 64;
    int idx = base + (lane < m ? lane : m - 1);  // clamp keeps csr loads in-bounds
    int sn_v = csr_src[idx];
    float w_v = csr_w[idx];
    for (int j = 0; j < m; ++j) {
      int sn = __builtin_amdgcn_readlane(sn_v, j);
      float w = __uint_as_float((unsigned)__builtin_amdgcn_readlane((int)__float_as_uint(w_v), j));
      __half2 hv = *reinterpret_cast<const __half2*>(h + sn * HID + lane * 2);
      float2 f = __half22float2(hv);
      ax += w * f.x;
      ay += w * f.y;
    }
  }
  unsigned short hx = f32_to_bf16_rne(ax);
  unsigned short lx = f32_to_bf16_rne(ax - bf16_to_f32(hx));
  unsigned short hy = f32_to_bf16_rne(ay);
  unsigned short ly = f32_to_bf16_rne(ay - bf16_to_f32(hy));
  ushort2 hv2 = {hx, hy}, lv2 = {lx, ly};
  *reinterpret_cast<ushort2*>(aggh + wid * HID + lane * 2) = hv2;
  *reinterpret_cast<ushort2*>(aggl + wid * HID + lane * 2) = lv2;
}

// ---------------- per-layer: h = relu(agg @ W^T + b * wsum) via split-bf16 MFMA ----------
// wave = 16 nodes x 128 outputs, K=128. a*w ~= ah*wh + ah*wl + al*wh (fp32 acc).
// D: col(kout)=lane&15, row(node)=(lane>>4)*4+reg  [guide §3, m89-verified].
__global__ void __launch_bounds__(256) mfma_linear_kernel(
    const unsigned short* __restrict__ aggh, const unsigned short* __restrict__ aggl,
    const unsigned short* __restrict__ whi, const unsigned short* __restrict__ wlo,
    const float* __restrict__ wsum, const float* __restrict__ b, __half* __restrict__ h) {
  int wave = threadIdx.x >> 6;
  int lane = threadIdx.x & 63;
  int node0 = blockIdx.x * 64 + wave * 16;
  int mrow = lane & 15;
  int kc = (lane >> 4) * 8;

  const unsigned short* pah = aggh + (node0 + mrow) * HID;
  const unsigned short* pal = aggl + (node0 + mrow) * HID;

  f32x4 acc[8];
#pragma unroll
  for (int t = 0; t < 8; ++t) acc[t] = (f32x4){0.f, 0.f, 0.f, 0.f};

#pragma unroll
  for (int s = 0; s < 4; ++s) {
    int joff = s * 32 + kc;
    bf16x8 ah = *reinterpret_cast<const bf16x8*>(pah + joff);
    bf16x8 al = *reinterpret_cast<const bf16x8*>(pal + joff);
#pragma unroll
    for (int t = 0; t < 8; ++t) {
      bf16x8 bh = *reinterpret_cast<const bf16x8*>(whi + (t * 16 + mrow) * HID + joff);
      bf16x8 bl = *reinterpret_cast<const bf16x8*>(wlo + (t * 16 + mrow) * HID + joff);
      acc[t] = __builtin_amdgcn_mfma_f32_16x16x32_bf16(ah, bh, acc[t], 0, 0, 0);
      acc[t] = __builtin_amdgcn_mfma_f32_16x16x32_bf16(ah, bl, acc[t], 0, 0, 0);
      acc[t] = __builtin_amdgcn_mfma_f32_16x16x32_bf16(al, bh, acc[t], 0, 0, 0);
    }
  }

  int nodeBase = node0 + (lane >> 4) * 4;
  float ws4[4];
#pragma unroll
  for (int r = 0; r < 4; ++r) ws4[r] = wsum[nodeBase + r];
#pragma unroll
  for (int t = 0; t < 8; ++t) {
    int kout = t * 16 + mrow;
    float bk = b[kout];
#pragma unroll
    for (int r = 0; r < 4; ++r) {
      float v = acc[t][r] + bk * ws4[r];
      h[(nodeBase + r) * HID + kout] = __float2half(fmaxf(v, 0.f));
    }
  }
}

// ---------------- cluster softmax head (wave per node) ----------------
__global__ void cluster_kernel(const __half* __restrict__ h, const float* __restrict__ cW,
                               const float* __restrict__ cb, float* __restrict__ out) {
  int wid = (blockIdx.x * blockDim.x + threadIdx.x) >> 6;
  int lane = threadIdx.x & 63;
  if (wid >= NN) return;
  float h0 = __half2float(h[wid * HID + lane]);
  float h1 = __half2float(h[wid * HID + 64 + lane]);
  float logit[3];
#pragma unroll
  for (int c = 0; c < 3; ++c) {
    float p = h0 * cW[c * HID + lane] + h1 * cW[c * HID + 64 + lane];
#pragma unroll
    for (int off = 32; off > 0; off >>= 1) p += __shfl_xor(p, off, 64);
    logit[c] = p + cb[c];
  }
  if (lane == 0) {
    float m = fmaxf(logit[0], fmaxf(logit[1], logit[2]));
    float e0 = expf(logit[0] - m), e1 = expf(logit[1] - m), e2 = expf(logit[2] - m);
    float inv = 1.0f / (e0 + e1 + e2);
    out[wid * 3 + 0] = e0 * inv;
    out[wid * 3 + 1] = e1 * inv;
    out[wid * 3 + 2] = e2 * inv;
  }
}

// ---------------- energy head: two-stage column reduction ----------------
__global__ void colsum_part_kernel(const __half* __restrict__ h, float* __restrict__ partial) {
  int t = threadIdx.x;
  int col = t & 127;
  int lane_id = blockIdx.x * 2 + (t >> 7);  // [0, 2048)
  float acc = 0.f;
  for (int r = lane_id; r < NN; r += 2048) acc += __half2float(h[r * HID + col]);
  partial[lane_id * HID + col] = acc;
}

__global__ void energy_final_kernel(const float* __restrict__ partial,
                                    const float* __restrict__ eW, const float* __restrict__ eb,
                                    float* __restrict__ out) {
  __shared__ float sh[8][HID];
  __shared__ float red[2];
  int t = threadIdx.x;
  int col = t & 127;
  int slot = t >> 7;  // 0..7
  float acc = 0.f;
  for (int i = 0; i < 256; ++i) acc += partial[(slot + 8 * i) * HID + col];
  sh[slot][col] = acc;
  __syncthreads();
  if (t < 128) {
    float s = 0.f;
#pragma unroll
    for (int j = 0; j < 8; ++j) s += sh[j][t];
    float v = s * (1.0f / NN) * eW[t];
#pragma unroll
    for (int off = 32; off > 0; off >>= 1) v += __shfl_xor(v, off, 64);
    if ((t & 63) == 0) red[t >> 6] = v;
  }
  __syncthreads();
  if (t == 0) {
    float e = red[0] + red[1] + eb[0];
    out[NN * 3] = e;
    out[NN * 3 + 1] = (e < -1.0f) ? 1.0f : 0.0f;
  }
}

extern "C" void kernel_launch(void* const* d_in, const int* in_sizes, int n_in,
                              void* d_out, int out_size, void* d_ws, size_t ws_size,
                              hipStream_t stream) {
  const float* x    = (const float*)d_in[0];
  const int*   ei   = (const int*)d_in[1];
  const float* dist = (const float*)d_in[2];
  const float* encW = (const float*)d_in[3];
  const float* encb = (const float*)d_in[4];
  const float* convW = (const float*)d_in[5];
  const float* convb = (const float*)d_in[6];
  const float* cW   = (const float*)d_in[7];
  const float* cb   = (const float*)d_in[8];
  const float* eW   = (const float*)d_in[9];
  const float* eb   = (const float*)d_in[10];
  float* out = (float*)d_out;

  // workspace layout (bytes)
  char* ws = (char*)d_ws;
  __half*         h       = (__half*)        (ws + 0);           // 10,240,000
  unsigned short* aggh    = (unsigned short*)(ws + 10240000);    // 10,240,000
  unsigned short* aggl    = (unsigned short*)(ws + 20480000);    // 10,240,000
  int*            csr_src = (int*)           (ws + 30720000);    //  2,560,000
  float*          csr_w   = (float*)         (ws + 33280000);    //  2,560,000
  int*            row_ptr = (int*)           (ws + 35840000);    //    160,064
  int*            cnt     = (int*)           (ws + 36000064);    //    160,000
  int*            fill    = (int*)           (ws + 36160064);    //    160,000
  float*          wsum    = (float*)         (ws + 36320064);    //    160,000
  unsigned short* whi5    = (unsigned short*)(ws + 36480064);    //    163,840
  unsigned short* wlo5    = (unsigned short*)(ws + 36643904);    //    163,840
  if (ws_size < (size_t)36807744) return;  // insufficient scratch — fail visibly

  // aggh region is dead until the first aggregate -> scan scratch lives there;
  // and dead again after the last mfma_linear -> colsum partials live there.
  int*   blocksum = (int*)aggh;
  int*   blockoff = (int*)aggh + 512;
  float* partial  = (float*)aggh;  // 2048*128 floats = 1 MB

  const int* srcI = ei;
  const int* dstI = ei + NE;

  hipMemsetAsync(cnt, 0, 320000, stream);  // cnt + fill (contiguous)

  encoder_kernel<<<(NN * HID + 255) / 256, 256, 0, stream>>>(x, encW, encb, h);
  wconv_kernel<<<(NL * HID * HID + 255) / 256, 256, 0, stream>>>(convW, whi5, wlo5);

  hist_kernel<<<(NE + 255) / 256, 256, 0, stream>>>(dstI, cnt);
  partial_kernel<<<NBLK, 256, 0, stream>>>(cnt, blocksum);
  scan_small_kernel<<<1, 256, 0, stream>>>(blocksum, blockoff, row_ptr);
  rowptr_kernel<<<NBLK, 256, 0, stream>>>(cnt, blockoff, row_ptr);
  scatter_kernel<<<(NE + 255) / 256, 256, 0, stream>>>(srcI, dstI, dist, row_ptr, fill,
                                                       csr_src, csr_w);
  wsum_kernel<<<(NN + 255) / 256, 256, 0, stream>>>(row_ptr, csr_w, wsum);

  for (int l = 0; l < NL; ++l) {
    aggregate_kernel<<<(NN * 64 + 255) / 256, 256, 0, stream>>>(h, row_ptr, csr_src, csr_w,
                                                                aggh, aggl);
    mfma_linear_kernel<<<NN / 64, 256, 0, stream>>>(aggh, aggl,
                                                    whi5 + (size_t)l * HID * HID,
                                                    wlo5 + (size_t)l * HID * HID,
                                                    wsum, convb + (size_t)l * HID, h);
  }

  cluster_kernel<<<(NN * 64 + 255) / 256, 256, 0, stream>>>(h, cW, cb, out);
  colsum_part_kernel<<<1024, 256, 0, stream>>>(h, partial);
  energy_final_kernel<<<1, 1024, 0, stream>>>(partial, eW, eb, out);
}

// Round 7
// 438.506 us; speedup vs baseline: 1.9182x; 1.1309x over previous
//
#include <hip/hip_runtime.h>
#include <hip/hip_fp16.h>

#define NN 40000
#define NE 640000
#define HID 128
#define NL 5
#define NBLK 157  // ceil(40000/256)

typedef __attribute__((ext_vector_type(8))) short bf16x8;
typedef __attribute__((ext_vector_type(4))) float f32x4;

static __device__ __forceinline__ unsigned short f32_to_bf16_rne(float f) {
  unsigned int u = __float_as_uint(f);
  unsigned int lsb = (u >> 16) & 1u;
  u += 0x7fffu + lsb;
  return (unsigned short)(u >> 16);
}
static __device__ __forceinline__ float bf16_to_f32(unsigned short s) {
  return __uint_as_float(((unsigned int)s) << 16);
}

// ---------------- encoder: h[n][k] = x[n][:7] . encW[k][:7] + encb[k] (fp16 out) ------
__global__ void encoder_kernel(const float* __restrict__ x, const float* __restrict__ W,
                               const float* __restrict__ b, __half* __restrict__ h) {
  int gid = blockIdx.x * blockDim.x + threadIdx.x;
  if (gid >= NN * HID) return;
  int n = gid >> 7, k = gid & 127;
  const float* xp = x + n * 7;
  const float* wp = W + k * 7;
  float acc = b[k];
#pragma unroll
  for (int i = 0; i < 7; ++i) acc += xp[i] * wp[i];
  h[gid] = __float2half(acc);
}

// ---------------- split all 5 conv_W into bf16 hi/lo planes ----------------
__global__ void wconv_kernel(const float* __restrict__ W, unsigned short* __restrict__ whi,
                             unsigned short* __restrict__ wlo) {
  int i = blockIdx.x * 256 + threadIdx.x;
  if (i >= NL * HID * HID) return;
  float w = W[i];
  unsigned short hi = f32_to_bf16_rne(w);
  unsigned short lo = f32_to_bf16_rne(w - bf16_to_f32(hi));
  whi[i] = hi;
  wlo[i] = lo;
}

// ---------------- CSR build ----------------
__global__ void hist_kernel(const int* __restrict__ dst, int* __restrict__ cnt) {
  int e = blockIdx.x * blockDim.x + threadIdx.x;
  if (e < NE) atomicAdd(&cnt[dst[e]], 1);
}

__global__ void partial_kernel(const int* __restrict__ cnt, int* __restrict__ blocksum) {
  __shared__ int red[4];
  int t = threadIdx.x;
  int idx = blockIdx.x * 256 + t;
  int v = idx < NN ? cnt[idx] : 0;
#pragma unroll
  for (int off = 32; off > 0; off >>= 1) v += __shfl_xor(v, off, 64);
  if ((t & 63) == 0) red[t >> 6] = v;
  __syncthreads();
  if (t == 0) blocksum[blockIdx.x] = red[0] + red[1] + red[2] + red[3];
}

__global__ void scan_small_kernel(const int* __restrict__ blocksum, int* __restrict__ blockoff,
                                  int* __restrict__ row_ptr) {
  __shared__ int sh[256];
  int t = threadIdx.x;
  int v = t < NBLK ? blocksum[t] : 0;
  sh[t] = v;
  __syncthreads();
  for (int off = 1; off < 256; off <<= 1) {
    int u = (t >= off) ? sh[t - off] : 0;
    __syncthreads();
    sh[t] += u;
    __syncthreads();
  }
  if (t < NBLK) blockoff[t] = sh[t] - v;
  if (t == 255) row_ptr[NN] = sh[255];
}

__global__ void rowptr_kernel(const int* __restrict__ cnt, const int* __restrict__ blockoff,
                              int* __restrict__ row_ptr) {
  __shared__ int sh[256];
  int t = threadIdx.x;
  int idx = blockIdx.x * 256 + t;
  int v = idx < NN ? cnt[idx] : 0;
  sh[t] = v;
  __syncthreads();
  for (int off = 1; off < 256; off <<= 1) {
    int u = (t >= off) ? sh[t - off] : 0;
    __syncthreads();
    sh[t] += u;
    __syncthreads();
  }
  if (idx < NN) row_ptr[idx] = blockoff[blockIdx.x] + sh[t] - v;
}

// packed (src, w_bits) payload: ONE 8B scattered store per edge (halves the
// number of dirty 64B lines vs two 4B stores into separate arrays).
__global__ void scatter_kernel(const int* __restrict__ src, const int* __restrict__ dst,
                               const float* __restrict__ dist,
                               const int* __restrict__ row_ptr, int* __restrict__ fill,
                               int2* __restrict__ csr_ew) {
  int e = blockIdx.x * blockDim.x + threadIdx.x;
  if (e >= NE) return;
  int d = dst[e];
  int pos = row_ptr[d] + atomicAdd(&fill[d], 1);
  float dd = dist[e] + 1e-6f;
  float w = 1.0f / (dd * dd);
  csr_ew[pos] = make_int2(src[e], (int)__float_as_uint(w));
}

__global__ void wsum_kernel(const int* __restrict__ row_ptr, const int2* __restrict__ csr_ew,
                            float* __restrict__ wsum) {
  int n = blockIdx.x * blockDim.x + threadIdx.x;
  if (n >= NN) return;
  int s = row_ptr[n], e = row_ptr[n + 1];
  float acc = 0.f;
  for (int i = s; i < e; ++i) acc += __uint_as_float((unsigned)csr_ew[i].y);
  wsum[n] = acc;
}

// ---------------- per-layer: aggregate (wave per node, 2 edges/iter) ----------------
// Lanes 0-31 process edge j, lanes 32-63 edge j+1; each lane gathers 8B (4 fp16
// cols). Halves loop trips + doubles bytes/load vs 1-edge/iter. CSR chunk is
// preloaded 64-wide as packed int2; per-edge broadcast via __shfl (bpermute).
__global__ void aggregate_kernel(const __half* __restrict__ h, const int* __restrict__ row_ptr,
                                 const int2* __restrict__ csr_ew,
                                 unsigned short* __restrict__ aggh,
                                 unsigned short* __restrict__ aggl) {
  int wid = (blockIdx.x * blockDim.x + threadIdx.x) >> 6;
  int lane = threadIdx.x & 63;
  if (wid >= NN) return;
  int half = lane >> 5;  // which edge of the pair
  int sub = lane & 31;   // column group: cols [4*sub, 4*sub+3]
  int s = row_ptr[wid], e = row_ptr[wid + 1];
  float a0 = 0.f, a1 = 0.f, a2 = 0.f, a3 = 0.f;
  for (int base = s; base < e; base += 64) {
    int m = e - base;
    if (m > 64) m = 64;
    int idx = base + (lane < m ? lane : m - 1);  // clamp keeps csr loads in-bounds
    int2 p = csr_ew[idx];
    for (int j = 0; j < m; j += 2) {
      int jj = j + half;
      int jc = jj < m ? jj : m - 1;
      int sn = __shfl(p.x, jc, 64);
      float w = __uint_as_float((unsigned)__shfl(p.y, jc, 64));
      if (jj >= m) w = 0.f;
      uint2 u = *reinterpret_cast<const uint2*>(h + sn * HID + sub * 4);
      float2 fa = __half22float2(*reinterpret_cast<__half2*>(&u.x));
      float2 fb = __half22float2(*reinterpret_cast<__half2*>(&u.y));
      a0 += w * fa.x;
      a1 += w * fa.y;
      a2 += w * fb.x;
      a3 += w * fb.y;
    }
  }
  // combine the two half-wave partial sums
  a0 += __shfl_xor(a0, 32, 64);
  a1 += __shfl_xor(a1, 32, 64);
  a2 += __shfl_xor(a2, 32, 64);
  a3 += __shfl_xor(a3, 32, 64);
  if (half == 0) {
    unsigned short h0 = f32_to_bf16_rne(a0), l0 = f32_to_bf16_rne(a0 - bf16_to_f32(h0));
    unsigned short h1 = f32_to_bf16_rne(a1), l1 = f32_to_bf16_rne(a1 - bf16_to_f32(h1));
    unsigned short h2 = f32_to_bf16_rne(a2), l2 = f32_to_bf16_rne(a2 - bf16_to_f32(h2));
    unsigned short h3 = f32_to_bf16_rne(a3), l3 = f32_to_bf16_rne(a3 - bf16_to_f32(h3));
    ushort4 hv = {h0, h1, h2, h3}, lv = {l0, l1, l2, l3};
    *reinterpret_cast<ushort4*>(aggh + wid * HID + sub * 4) = hv;
    *reinterpret_cast<ushort4*>(aggl + wid * HID + sub * 4) = lv;
  }
}

// ---------------- per-layer: h = relu(agg @ W^T + b * wsum) via split-bf16 MFMA ----------
// wave = 16 nodes x 128 outputs, K=128. a*w ~= ah*wh + ah*wl + al*wh (fp32 acc).
// D: col(kout)=lane&15, row(node)=(lane>>4)*4+reg  [guide §3, m89-verified].
__global__ void __launch_bounds__(256) mfma_linear_kernel(
    const unsigned short* __restrict__ aggh, const unsigned short* __restrict__ aggl,
    const unsigned short* __restrict__ whi, const unsigned short* __restrict__ wlo,
    const float* __restrict__ wsum, const float* __restrict__ b, __half* __restrict__ h) {
  int wave = threadIdx.x >> 6;
  int lane = threadIdx.x & 63;
  int node0 = blockIdx.x * 64 + wave * 16;
  int mrow = lane & 15;
  int kc = (lane >> 4) * 8;

  const unsigned short* pah = aggh + (node0 + mrow) * HID;
  const unsigned short* pal = aggl + (node0 + mrow) * HID;

  f32x4 acc[8];
#pragma unroll
  for (int t = 0; t < 8; ++t) acc[t] = (f32x4){0.f, 0.f, 0.f, 0.f};

#pragma unroll
  for (int s = 0; s < 4; ++s) {
    int joff = s * 32 + kc;
    bf16x8 ah = *reinterpret_cast<const bf16x8*>(pah + joff);
    bf16x8 al = *reinterpret_cast<const bf16x8*>(pal + joff);
#pragma unroll
    for (int t = 0; t < 8; ++t) {
      bf16x8 bh = *reinterpret_cast<const bf16x8*>(whi + (t * 16 + mrow) * HID + joff);
      bf16x8 bl = *reinterpret_cast<const bf16x8*>(wlo + (t * 16 + mrow) * HID + joff);
      acc[t] = __builtin_amdgcn_mfma_f32_16x16x32_bf16(ah, bh, acc[t], 0, 0, 0);
      acc[t] = __builtin_amdgcn_mfma_f32_16x16x32_bf16(ah, bl, acc[t], 0, 0, 0);
      acc[t] = __builtin_amdgcn_mfma_f32_16x16x32_bf16(al, bh, acc[t], 0, 0, 0);
    }
  }

  int nodeBase = node0 + (lane >> 4) * 4;
  float ws4[4];
#pragma unroll
  for (int r = 0; r < 4; ++r) ws4[r] = wsum[nodeBase + r];
#pragma unroll
  for (int t = 0; t < 8; ++t) {
    int kout = t * 16 + mrow;
    float bk = b[kout];
#pragma unroll
    for (int r = 0; r < 4; ++r) {
      float v = acc[t][r] + bk * ws4[r];
      h[(nodeBase + r) * HID + kout] = __float2half(fmaxf(v, 0.f));
    }
  }
}

// ---------------- cluster softmax head (wave per node) ----------------
__global__ void cluster_kernel(const __half* __restrict__ h, const float* __restrict__ cW,
                               const float* __restrict__ cb, float* __restrict__ out) {
  int wid = (blockIdx.x * blockDim.x + threadIdx.x) >> 6;
  int lane = threadIdx.x & 63;
  if (wid >= NN) return;
  float h0 = __half2float(h[wid * HID + lane]);
  float h1 = __half2float(h[wid * HID + 64 + lane]);
  float logit[3];
#pragma unroll
  for (int c = 0; c < 3; ++c) {
    float p = h0 * cW[c * HID + lane] + h1 * cW[c * HID + 64 + lane];
#pragma unroll
    for (int off = 32; off > 0; off >>= 1) p += __shfl_xor(p, off, 64);
    logit[c] = p + cb[c];
  }
  if (lane == 0) {
    float m = fmaxf(logit[0], fmaxf(logit[1], logit[2]));
    float e0 = expf(logit[0] - m), e1 = expf(logit[1] - m), e2 = expf(logit[2] - m);
    float inv = 1.0f / (e0 + e1 + e2);
    out[wid * 3 + 0] = e0 * inv;
    out[wid * 3 + 1] = e1 * inv;
    out[wid * 3 + 2] = e2 * inv;
  }
}

// ---------------- energy head: two-stage column reduction ----------------
__global__ void colsum_part_kernel(const __half* __restrict__ h, float* __restrict__ partial) {
  int t = threadIdx.x;
  int col = t & 127;
  int lane_id = blockIdx.x * 2 + (t >> 7);  // [0, 2048)
  float acc = 0.f;
  for (int r = lane_id; r < NN; r += 2048) acc += __half2float(h[r * HID + col]);
  partial[lane_id * HID + col] = acc;
}

__global__ void energy_final_kernel(const float* __restrict__ partial,
                                    const float* __restrict__ eW, const float* __restrict__ eb,
                                    float* __restrict__ out) {
  __shared__ float sh[8][HID];
  __shared__ float red[2];
  int t = threadIdx.x;
  int col = t & 127;
  int slot = t >> 7;  // 0..7
  float acc = 0.f;
  for (int i = 0; i < 256; ++i) acc += partial[(slot + 8 * i) * HID + col];
  sh[slot][col] = acc;
  __syncthreads();
  if (t < 128) {
    float s = 0.f;
#pragma unroll
    for (int j = 0; j < 8; ++j) s += sh[j][t];
    float v = s * (1.0f / NN) * eW[t];
#pragma unroll
    for (int off = 32; off > 0; off >>= 1) v += __shfl_xor(v, off, 64);
    if ((t & 63) == 0) red[t >> 6] = v;
  }
  __syncthreads();
  if (t == 0) {
    float e = red[0] + red[1] + eb[0];
    out[NN * 3] = e;
    out[NN * 3 + 1] = (e < -1.0f) ? 1.0f : 0.0f;
  }
}

extern "C" void kernel_launch(void* const* d_in, const int* in_sizes, int n_in,
                              void* d_out, int out_size, void* d_ws, size_t ws_size,
                              hipStream_t stream) {
  const float* x    = (const float*)d_in[0];
  const int*   ei   = (const int*)d_in[1];
  const float* dist = (const float*)d_in[2];
  const float* encW = (const float*)d_in[3];
  const float* encb = (const float*)d_in[4];
  const float* convW = (const float*)d_in[5];
  const float* convb = (const float*)d_in[6];
  const float* cW   = (const float*)d_in[7];
  const float* cb   = (const float*)d_in[8];
  const float* eW   = (const float*)d_in[9];
  const float* eb   = (const float*)d_in[10];
  float* out = (float*)d_out;

  // workspace layout (bytes)
  char* ws = (char*)d_ws;
  __half*         h       = (__half*)        (ws + 0);           // 10,240,000
  unsigned short* aggh    = (unsigned short*)(ws + 10240000);    // 10,240,000
  unsigned short* aggl    = (unsigned short*)(ws + 20480000);    // 10,240,000
  int2*           csr_ew  = (int2*)          (ws + 30720000);    //  5,120,000
  int*            row_ptr = (int*)           (ws + 35840000);    //    160,064
  int*            cnt     = (int*)           (ws + 36000064);    //    160,000
  int*            fill    = (int*)           (ws + 36160064);    //    160,000
  float*          wsum    = (float*)         (ws + 36320064);    //    160,000
  unsigned short* whi5    = (unsigned short*)(ws + 36480064);    //    163,840
  unsigned short* wlo5    = (unsigned short*)(ws + 36643904);    //    163,840
  if (ws_size < (size_t)36807744) return;  // insufficient scratch — fail visibly

  // aggh region is dead until the first aggregate -> scan scratch lives there;
  // and dead again after the last mfma_linear -> colsum partials live there.
  int*   blocksum = (int*)aggh;
  int*   blockoff = (int*)aggh + 512;
  float* partial  = (float*)aggh;  // 2048*128 floats = 1 MB

  const int* srcI = ei;
  const int* dstI = ei + NE;

  hipMemsetAsync(cnt, 0, 320000, stream);  // cnt + fill (contiguous)

  encoder_kernel<<<(NN * HID + 255) / 256, 256, 0, stream>>>(x, encW, encb, h);
  wconv_kernel<<<(NL * HID * HID + 255) / 256, 256, 0, stream>>>(convW, whi5, wlo5);

  hist_kernel<<<(NE + 255) / 256, 256, 0, stream>>>(dstI, cnt);
  partial_kernel<<<NBLK, 256, 0, stream>>>(cnt, blocksum);
  scan_small_kernel<<<1, 256, 0, stream>>>(blocksum, blockoff, row_ptr);
  rowptr_kernel<<<NBLK, 256, 0, stream>>>(cnt, blockoff, row_ptr);
  scatter_kernel<<<(NE + 255) / 256, 256, 0, stream>>>(srcI, dstI, dist, row_ptr, fill, csr_ew);
  wsum_kernel<<<(NN + 255) / 256, 256, 0, stream>>>(row_ptr, csr_ew, wsum);

  for (int l = 0; l < NL; ++l) {
    aggregate_kernel<<<(NN * 64 + 255) / 256, 256, 0, stream>>>(h, row_ptr, csr_ew, aggh, aggl);
    mfma_linear_kernel<<<NN / 64, 256, 0, stream>>>(aggh, aggl,
                                                    whi5 + (size_t)l * HID * HID,
                                                    wlo5 + (size_t)l * HID * HID,
                                                    wsum, convb + (size_t)l * HID, h);
  }

  cluster_kernel<<<(NN * 64 + 255) / 256, 256, 0, stream>>>(h, cW, cb, out);
  colsum_part_kernel<<<1024, 256, 0, stream>>>(h, partial);
  energy_final_kernel<<<1, 1024, 0, stream>>>(partial, eW, eb, out);
}

// Round 8
// 416.691 us; speedup vs baseline: 2.0186x; 1.0524x over previous
//
#include <hip/hip_runtime.h>
#include <hip/hip_fp16.h>

#define NN 40000
#define NE 640000
#define HID 128
#define NL 5
#define NBLK 157  // ceil(40000/256)

typedef __attribute__((ext_vector_type(8))) short bf16x8;
typedef __attribute__((ext_vector_type(4))) float f32x4;

static __device__ __forceinline__ unsigned short f32_to_bf16_rne(float f) {
  unsigned int u = __float_as_uint(f);
  unsigned int lsb = (u >> 16) & 1u;
  u += 0x7fffu + lsb;
  return (unsigned short)(u >> 16);
}
static __device__ __forceinline__ float bf16_to_f32(unsigned short s) {
  return __uint_as_float(((unsigned int)s) << 16);
}

// ---------------- encoder: h[n][k] = x[n][:7] . encW[k][:7] + encb[k] (fp16 out) ------
__global__ void encoder_kernel(const float* __restrict__ x, const float* __restrict__ W,
                               const float* __restrict__ b, __half* __restrict__ h) {
  int gid = blockIdx.x * blockDim.x + threadIdx.x;
  if (gid >= NN * HID) return;
  int n = gid >> 7, k = gid & 127;
  const float* xp = x + n * 7;
  const float* wp = W + k * 7;
  float acc = b[k];
#pragma unroll
  for (int i = 0; i < 7; ++i) acc += xp[i] * wp[i];
  h[gid] = __float2half(acc);
}

// ---------------- split all 5 conv_W into bf16 hi/lo planes ----------------
__global__ void wconv_kernel(const float* __restrict__ W, unsigned short* __restrict__ whi,
                             unsigned short* __restrict__ wlo) {
  int i = blockIdx.x * 256 + threadIdx.x;
  if (i >= NL * HID * HID) return;
  float w = W[i];
  unsigned short hi = f32_to_bf16_rne(w);
  unsigned short lo = f32_to_bf16_rne(w - bf16_to_f32(hi));
  whi[i] = hi;
  wlo[i] = lo;
}

// ---------------- CSR build ----------------
__global__ void hist_kernel(const int* __restrict__ dst, int* __restrict__ cnt) {
  int e = blockIdx.x * blockDim.x + threadIdx.x;
  if (e < NE) atomicAdd(&cnt[dst[e]], 1);
}

__global__ void partial_kernel(const int* __restrict__ cnt, int* __restrict__ blocksum) {
  __shared__ int red[4];
  int t = threadIdx.x;
  int idx = blockIdx.x * 256 + t;
  int v = idx < NN ? cnt[idx] : 0;
#pragma unroll
  for (int off = 32; off > 0; off >>= 1) v += __shfl_xor(v, off, 64);
  if ((t & 63) == 0) red[t >> 6] = v;
  __syncthreads();
  if (t == 0) blocksum[blockIdx.x] = red[0] + red[1] + red[2] + red[3];
}

__global__ void scan_small_kernel(const int* __restrict__ blocksum, int* __restrict__ blockoff,
                                  int* __restrict__ row_ptr) {
  __shared__ int sh[256];
  int t = threadIdx.x;
  int v = t < NBLK ? blocksum[t] : 0;
  sh[t] = v;
  __syncthreads();
  for (int off = 1; off < 256; off <<= 1) {
    int u = (t >= off) ? sh[t - off] : 0;
    __syncthreads();
    sh[t] += u;
    __syncthreads();
  }
  if (t < NBLK) blockoff[t] = sh[t] - v;
  if (t == 255) row_ptr[NN] = sh[255];
}

__global__ void rowptr_kernel(const int* __restrict__ cnt, const int* __restrict__ blockoff,
                              int* __restrict__ row_ptr) {
  __shared__ int sh[256];
  int t = threadIdx.x;
  int idx = blockIdx.x * 256 + t;
  int v = idx < NN ? cnt[idx] : 0;
  sh[t] = v;
  __syncthreads();
  for (int off = 1; off < 256; off <<= 1) {
    int u = (t >= off) ? sh[t - off] : 0;
    __syncthreads();
    sh[t] += u;
    __syncthreads();
  }
  if (idx < NN) row_ptr[idx] = blockoff[blockIdx.x] + sh[t] - v;
}

// packed (src, w_bits) payload, ONE 8B non-temporal store per edge (bypass L2
// write-back path for randomly-scattered lines).
__global__ void scatter_kernel(const int* __restrict__ src, const int* __restrict__ dst,
                               const float* __restrict__ dist,
                               const int* __restrict__ row_ptr, int* __restrict__ fill,
                               int2* __restrict__ csr_ew) {
  int e = blockIdx.x * blockDim.x + threadIdx.x;
  if (e >= NE) return;
  int d = dst[e];
  int pos = row_ptr[d] + atomicAdd(&fill[d], 1);
  float dd = dist[e] + 1e-6f;
  float w = 1.0f / (dd * dd);
  unsigned long long pv =
      ((unsigned long long)__float_as_uint(w) << 32) | (unsigned)src[e];
  __builtin_nontemporal_store((long long)pv, (long long*)&csr_ew[pos]);
}

__global__ void wsum_kernel(const int* __restrict__ row_ptr, const int2* __restrict__ csr_ew,
                            float* __restrict__ wsum) {
  int n = blockIdx.x * blockDim.x + threadIdx.x;
  if (n >= NN) return;
  int s = row_ptr[n], e = row_ptr[n + 1];
  float acc = 0.f;
  for (int i = s; i < e; ++i) acc += __uint_as_float((unsigned)csr_ew[i].y);
  wsum[n] = acc;
}

// ---------------- per-layer: aggregate (wave per node, 2 edges/step) ----------------
// Fixed 16-edge strips with an unrolled 8-step body: 8 independent gathers in
// flight per wave (the runtime-bounded loop previously collapsed to VGPR=12 and
// ~1 outstanding gather). Ragged tail handled by clamp + w=0 (exact FP: zero
// contributions vanish).
__global__ void aggregate_kernel(const __half* __restrict__ h, const int* __restrict__ row_ptr,
                                 const int2* __restrict__ csr_ew,
                                 unsigned short* __restrict__ aggh,
                                 unsigned short* __restrict__ aggl) {
  int wid = (blockIdx.x * blockDim.x + threadIdx.x) >> 6;
  int lane = threadIdx.x & 63;
  if (wid >= NN) return;
  int half = lane >> 5;  // which edge of the pair
  int sub = lane & 31;   // column group: cols [4*sub, 4*sub+3]
  int s = row_ptr[wid], e = row_ptr[wid + 1];
  float a0 = 0.f, a1 = 0.f, a2 = 0.f, a3 = 0.f;
  for (int base = s; base < e; base += 64) {
    int mm = e - base;
    if (mm > 64) mm = 64;
    int idx = base + (lane < mm ? lane : mm - 1);  // clamp keeps csr loads in-bounds
    int2 p = csr_ew[idx];
    for (int j0 = 0; j0 < mm; j0 += 16) {
#pragma unroll
      for (int u = 0; u < 8; ++u) {
        int jj = j0 + 2 * u + half;
        int jc = jj < mm ? jj : mm - 1;
        int sn = __shfl(p.x, jc, 64);
        float w = __uint_as_float((unsigned)__shfl(p.y, jc, 64));
        if (jj >= mm) w = 0.f;
        uint2 v = *reinterpret_cast<const uint2*>(h + sn * HID + sub * 4);
        float2 fa = __half22float2(*reinterpret_cast<__half2*>(&v.x));
        float2 fb = __half22float2(*reinterpret_cast<__half2*>(&v.y));
        a0 += w * fa.x;
        a1 += w * fa.y;
        a2 += w * fb.x;
        a3 += w * fb.y;
      }
    }
  }
  // combine the two half-wave partial sums
  a0 += __shfl_xor(a0, 32, 64);
  a1 += __shfl_xor(a1, 32, 64);
  a2 += __shfl_xor(a2, 32, 64);
  a3 += __shfl_xor(a3, 32, 64);
  if (half == 0) {
    unsigned short h0 = f32_to_bf16_rne(a0), l0 = f32_to_bf16_rne(a0 - bf16_to_f32(h0));
    unsigned short h1 = f32_to_bf16_rne(a1), l1 = f32_to_bf16_rne(a1 - bf16_to_f32(h1));
    unsigned short h2 = f32_to_bf16_rne(a2), l2 = f32_to_bf16_rne(a2 - bf16_to_f32(h2));
    unsigned short h3 = f32_to_bf16_rne(a3), l3 = f32_to_bf16_rne(a3 - bf16_to_f32(h3));
    ushort4 hv = {h0, h1, h2, h3}, lv = {l0, l1, l2, l3};
    *reinterpret_cast<ushort4*>(aggh + wid * HID + sub * 4) = hv;
    *reinterpret_cast<ushort4*>(aggl + wid * HID + sub * 4) = lv;
  }
}

// ---------------- per-layer: h = relu(agg @ W^T + b * wsum) via split-bf16 MFMA ----------
// wave = 16 nodes x 128 outputs, K=128. a*w ~= ah*wh + ah*wl + al*wh (fp32 acc).
// D: col(kout)=lane&15, row(node)=(lane>>4)*4+reg  [guide §3, m89-verified].
__global__ void __launch_bounds__(256) mfma_linear_kernel(
    const unsigned short* __restrict__ aggh, const unsigned short* __restrict__ aggl,
    const unsigned short* __restrict__ whi, const unsigned short* __restrict__ wlo,
    const float* __restrict__ wsum, const float* __restrict__ b, __half* __restrict__ h) {
  int wave = threadIdx.x >> 6;
  int lane = threadIdx.x & 63;
  int node0 = blockIdx.x * 64 + wave * 16;
  int mrow = lane & 15;
  int kc = (lane >> 4) * 8;

  const unsigned short* pah = aggh + (node0 + mrow) * HID;
  const unsigned short* pal = aggl + (node0 + mrow) * HID;

  f32x4 acc[8];
#pragma unroll
  for (int t = 0; t < 8; ++t) acc[t] = (f32x4){0.f, 0.f, 0.f, 0.f};

#pragma unroll
  for (int s = 0; s < 4; ++s) {
    int joff = s * 32 + kc;
    bf16x8 ah = *reinterpret_cast<const bf16x8*>(pah + joff);
    bf16x8 al = *reinterpret_cast<const bf16x8*>(pal + joff);
#pragma unroll
    for (int t = 0; t < 8; ++t) {
      bf16x8 bh = *reinterpret_cast<const bf16x8*>(whi + (t * 16 + mrow) * HID + joff);
      bf16x8 bl = *reinterpret_cast<const bf16x8*>(wlo + (t * 16 + mrow) * HID + joff);
      acc[t] = __builtin_amdgcn_mfma_f32_16x16x32_bf16(ah, bh, acc[t], 0, 0, 0);
      acc[t] = __builtin_amdgcn_mfma_f32_16x16x32_bf16(ah, bl, acc[t], 0, 0, 0);
      acc[t] = __builtin_amdgcn_mfma_f32_16x16x32_bf16(al, bh, acc[t], 0, 0, 0);
    }
  }

  int nodeBase = node0 + (lane >> 4) * 4;
  float ws4[4];
#pragma unroll
  for (int r = 0; r < 4; ++r) ws4[r] = wsum[nodeBase + r];
#pragma unroll
  for (int t = 0; t < 8; ++t) {
    int kout = t * 16 + mrow;
    float bk = b[kout];
#pragma unroll
    for (int r = 0; r < 4; ++r) {
      float v = acc[t][r] + bk * ws4[r];
      h[(nodeBase + r) * HID + kout] = __float2half(fmaxf(v, 0.f));
    }
  }
}

// ---------------- cluster softmax head (wave per node) ----------------
__global__ void cluster_kernel(const __half* __restrict__ h, const float* __restrict__ cW,
                               const float* __restrict__ cb, float* __restrict__ out) {
  int wid = (blockIdx.x * blockDim.x + threadIdx.x) >> 6;
  int lane = threadIdx.x & 63;
  if (wid >= NN) return;
  float h0 = __half2float(h[wid * HID + lane]);
  float h1 = __half2float(h[wid * HID + 64 + lane]);
  float logit[3];
#pragma unroll
  for (int c = 0; c < 3; ++c) {
    float p = h0 * cW[c * HID + lane] + h1 * cW[c * HID + 64 + lane];
#pragma unroll
    for (int off = 32; off > 0; off >>= 1) p += __shfl_xor(p, off, 64);
    logit[c] = p + cb[c];
  }
  if (lane == 0) {
    float m = fmaxf(logit[0], fmaxf(logit[1], logit[2]));
    float e0 = expf(logit[0] - m), e1 = expf(logit[1] - m), e2 = expf(logit[2] - m);
    float inv = 1.0f / (e0 + e1 + e2);
    out[wid * 3 + 0] = e0 * inv;
    out[wid * 3 + 1] = e1 * inv;
    out[wid * 3 + 2] = e2 * inv;
  }
}

// ---------------- energy head: two-stage column reduction ----------------
__global__ void colsum_part_kernel(const __half* __restrict__ h, float* __restrict__ partial) {
  int t = threadIdx.x;
  int col = t & 127;
  int lane_id = blockIdx.x * 2 + (t >> 7);  // [0, 2048)
  float acc = 0.f;
  for (int r = lane_id; r < NN; r += 2048) acc += __half2float(h[r * HID + col]);
  partial[lane_id * HID + col] = acc;
}

__global__ void energy_final_kernel(const float* __restrict__ partial,
                                    const float* __restrict__ eW, const float* __restrict__ eb,
                                    float* __restrict__ out) {
  __shared__ float sh[8][HID];
  __shared__ float red[2];
  int t = threadIdx.x;
  int col = t & 127;
  int slot = t >> 7;  // 0..7
  float acc = 0.f;
  for (int i = 0; i < 256; ++i) acc += partial[(slot + 8 * i) * HID + col];
  sh[slot][col] = acc;
  __syncthreads();
  if (t < 128) {
    float s = 0.f;
#pragma unroll
    for (int j = 0; j < 8; ++j) s += sh[j][t];
    float v = s * (1.0f / NN) * eW[t];
#pragma unroll
    for (int off = 32; off > 0; off >>= 1) v += __shfl_xor(v, off, 64);
    if ((t & 63) == 0) red[t >> 6] = v;
  }
  __syncthreads();
  if (t == 0) {
    float e = red[0] + red[1] + eb[0];
    out[NN * 3] = e;
    out[NN * 3 + 1] = (e < -1.0f) ? 1.0f : 0.0f;
  }
}

extern "C" void kernel_launch(void* const* d_in, const int* in_sizes, int n_in,
                              void* d_out, int out_size, void* d_ws, size_t ws_size,
                              hipStream_t stream) {
  const float* x    = (const float*)d_in[0];
  const int*   ei   = (const int*)d_in[1];
  const float* dist = (const float*)d_in[2];
  const float* encW = (const float*)d_in[3];
  const float* encb = (const float*)d_in[4];
  const float* convW = (const float*)d_in[5];
  const float* convb = (const float*)d_in[6];
  const float* cW   = (const float*)d_in[7];
  const float* cb   = (const float*)d_in[8];
  const float* eW   = (const float*)d_in[9];
  const float* eb   = (const float*)d_in[10];
  float* out = (float*)d_out;

  // workspace layout (bytes)
  char* ws = (char*)d_ws;
  __half*         h       = (__half*)        (ws + 0);           // 10,240,000
  unsigned short* aggh    = (unsigned short*)(ws + 10240000);    // 10,240,000
  unsigned short* aggl    = (unsigned short*)(ws + 20480000);    // 10,240,000
  int2*           csr_ew  = (int2*)          (ws + 30720000);    //  5,120,000
  int*            row_ptr = (int*)           (ws + 35840000);    //    160,064
  int*            cnt     = (int*)           (ws + 36000064);    //    160,000
  int*            fill    = (int*)           (ws + 36160064);    //    160,000
  float*          wsum    = (float*)         (ws + 36320064);    //    160,000
  unsigned short* whi5    = (unsigned short*)(ws + 36480064);    //    163,840
  unsigned short* wlo5    = (unsigned short*)(ws + 36643904);    //    163,840
  if (ws_size < (size_t)36807744) return;  // insufficient scratch — fail visibly

  // aggh region is dead until the first aggregate -> scan scratch lives there;
  // and dead again after the last mfma_linear -> colsum partials live there.
  int*   blocksum = (int*)aggh;
  int*   blockoff = (int*)aggh + 512;
  float* partial  = (float*)aggh;  // 2048*128 floats = 1 MB

  const int* srcI = ei;
  const int* dstI = ei + NE;

  hipMemsetAsync(cnt, 0, 320000, stream);  // cnt + fill (contiguous)

  encoder_kernel<<<(NN * HID + 255) / 256, 256, 0, stream>>>(x, encW, encb, h);
  wconv_kernel<<<(NL * HID * HID + 255) / 256, 256, 0, stream>>>(convW, whi5, wlo5);

  hist_kernel<<<(NE + 255) / 256, 256, 0, stream>>>(dstI, cnt);
  partial_kernel<<<NBLK, 256, 0, stream>>>(cnt, blocksum);
  scan_small_kernel<<<1, 256, 0, stream>>>(blocksum, blockoff, row_ptr);
  rowptr_kernel<<<NBLK, 256, 0, stream>>>(cnt, blockoff, row_ptr);
  scatter_kernel<<<(NE + 255) / 256, 256, 0, stream>>>(srcI, dstI, dist, row_ptr, fill, csr_ew);
  wsum_kernel<<<(NN + 255) / 256, 256, 0, stream>>>(row_ptr, csr_ew, wsum);

  for (int l = 0; l < NL; ++l) {
    aggregate_kernel<<<(NN * 64 + 255) / 256, 256, 0, stream>>>(h, row_ptr, csr_ew, aggh, aggl);
    mfma_linear_kernel<<<NN / 64, 256, 0, stream>>>(aggh, aggl,
                                                    whi5 + (size_t)l * HID * HID,
                                                    wlo5 + (size_t)l * HID * HID,
                                                    wsum, convb + (size_t)l * HID, h);
  }

  cluster_kernel<<<(NN * 64 + 255) / 256, 256, 0, stream>>>(h, cW, cb, out);
  colsum_part_kernel<<<1024, 256, 0, stream>>>(h, partial);
  energy_final_kernel<<<1, 1024, 0, stream>>>(partial, eW, eb, out);
}

// Round 9
// 413.346 us; speedup vs baseline: 2.0349x; 1.0081x over previous
//
#include <hip/hip_runtime.h>
#include <hip/hip_fp16.h>

#define NN 40000
#define NE 640000
#define HID 128
#define NL 5
#define NBLK 157  // ceil(40000/256)

typedef __attribute__((ext_vector_type(8))) short bf16x8;
typedef __attribute__((ext_vector_type(4))) float f32x4;

static __device__ __forceinline__ unsigned short f32_to_bf16_rne(float f) {
  unsigned int u = __float_as_uint(f);
  unsigned int lsb = (u >> 16) & 1u;
  u += 0x7fffu + lsb;
  return (unsigned short)(u >> 16);
}
static __device__ __forceinline__ float bf16_to_f32(unsigned short s) {
  return __uint_as_float(((unsigned int)s) << 16);
}

// ---------------- encoder: h[n][k] = x[n][:7] . encW[k][:7] + encb[k] (fp16 out) ------
__global__ void encoder_kernel(const float* __restrict__ x, const float* __restrict__ W,
                               const float* __restrict__ b, __half* __restrict__ h) {
  int gid = blockIdx.x * blockDim.x + threadIdx.x;
  if (gid >= NN * HID) return;
  int n = gid >> 7, k = gid & 127;
  const float* xp = x + n * 7;
  const float* wp = W + k * 7;
  float acc = b[k];
#pragma unroll
  for (int i = 0; i < 7; ++i) acc += xp[i] * wp[i];
  h[gid] = __float2half(acc);
}

// ---------------- split all 5 conv_W into bf16 hi/lo planes ----------------
__global__ void wconv_kernel(const float* __restrict__ W, unsigned short* __restrict__ whi,
                             unsigned short* __restrict__ wlo) {
  int i = blockIdx.x * 256 + threadIdx.x;
  if (i >= NL * HID * HID) return;
  float w = W[i];
  unsigned short hi = f32_to_bf16_rne(w);
  unsigned short lo = f32_to_bf16_rne(w - bf16_to_f32(hi));
  whi[i] = hi;
  wlo[i] = lo;
}

// ---------------- CSR build ----------------
// hist also captures each edge's rank within its dst (the atomic's return value)
// so scatter_kernel needs NO atomic at all.
__global__ void hist_kernel(const int* __restrict__ dst, int* __restrict__ cnt,
                            int* __restrict__ rank) {
  int e = blockIdx.x * blockDim.x + threadIdx.x;
  if (e < NE) rank[e] = atomicAdd(&cnt[dst[e]], 1);
}

__global__ void partial_kernel(const int* __restrict__ cnt, int* __restrict__ blocksum) {
  __shared__ int red[4];
  int t = threadIdx.x;
  int idx = blockIdx.x * 256 + t;
  int v = idx < NN ? cnt[idx] : 0;
#pragma unroll
  for (int off = 32; off > 0; off >>= 1) v += __shfl_xor(v, off, 64);
  if ((t & 63) == 0) red[t >> 6] = v;
  __syncthreads();
  if (t == 0) blocksum[blockIdx.x] = red[0] + red[1] + red[2] + red[3];
}

__global__ void scan_small_kernel(const int* __restrict__ blocksum, int* __restrict__ blockoff,
                                  int* __restrict__ row_ptr) {
  __shared__ int sh[256];
  int t = threadIdx.x;
  int v = t < NBLK ? blocksum[t] : 0;
  sh[t] = v;
  __syncthreads();
  for (int off = 1; off < 256; off <<= 1) {
    int u = (t >= off) ? sh[t - off] : 0;
    __syncthreads();
    sh[t] += u;
    __syncthreads();
  }
  if (t < NBLK) blockoff[t] = sh[t] - v;
  if (t == 255) row_ptr[NN] = sh[255];
}

__global__ void rowptr_kernel(const int* __restrict__ cnt, const int* __restrict__ blockoff,
                              int* __restrict__ row_ptr) {
  __shared__ int sh[256];
  int t = threadIdx.x;
  int idx = blockIdx.x * 256 + t;
  int v = idx < NN ? cnt[idx] : 0;
  sh[t] = v;
  __syncthreads();
  for (int off = 1; off < 256; off <<= 1) {
    int u = (t >= off) ? sh[t - off] : 0;
    __syncthreads();
    sh[t] += u;
    __syncthreads();
  }
  if (idx < NN) row_ptr[idx] = blockoff[blockIdx.x] + sh[t] - v;
}

// pure read + ONE 8B store per edge (no atomic: rank precomputed in hist).
__global__ void scatter_kernel(const int* __restrict__ src, const int* __restrict__ dst,
                               const float* __restrict__ dist,
                               const int* __restrict__ row_ptr, const int* __restrict__ rank,
                               int2* __restrict__ csr_ew) {
  int e = blockIdx.x * blockDim.x + threadIdx.x;
  if (e >= NE) return;
  int pos = row_ptr[dst[e]] + rank[e];
  float dd = dist[e] + 1e-6f;
  float w = 1.0f / (dd * dd);
  csr_ew[pos] = make_int2(src[e], (int)__float_as_uint(w));
}

__global__ void wsum_kernel(const int* __restrict__ row_ptr, const int2* __restrict__ csr_ew,
                            float* __restrict__ wsum) {
  int n = blockIdx.x * blockDim.x + threadIdx.x;
  if (n >= NN) return;
  int s = row_ptr[n], e = row_ptr[n + 1];
  float acc = 0.f;
  for (int i = s; i < e; ++i) acc += __uint_as_float((unsigned)csr_ew[i].y);
  wsum[n] = acc;
}

// ---------------- per-layer: aggregate (wave per node, scalar-uniform CSR) ----------
// Row bounds forced into SGPRs via readfirstlane -> csr_ew[i] is wave-uniform and
// compiles to s_load (scalar path); sn/w live in SGPRs so the h-gather is a
// global_load_dword with scalar base + lane offset. Unroll-16 keeps 16
// independent gathers in flight. Summation is in exact CSR order.
__global__ void aggregate_kernel(const __half* __restrict__ h, const int* __restrict__ row_ptr,
                                 const int2* __restrict__ csr_ew,
                                 unsigned short* __restrict__ aggh,
                                 unsigned short* __restrict__ aggl) {
  int wid = (blockIdx.x * blockDim.x + threadIdx.x) >> 6;
  int lane = threadIdx.x & 63;
  if (wid >= NN) return;
  int s = __builtin_amdgcn_readfirstlane(row_ptr[wid]);
  int e = __builtin_amdgcn_readfirstlane(row_ptr[wid + 1]);
  const __half* hp = h + lane * 2;  // this lane's 2 columns
  float ax = 0.f, ay = 0.f;
  int i = s;
  for (; i + 16 <= e; i += 16) {
#pragma unroll
    for (int u = 0; u < 16; ++u) {
      int2 p = csr_ew[i + u];
      int sn = p.x;
      float w = __uint_as_float((unsigned)p.y);
      float2 f = __half22float2(*reinterpret_cast<const __half2*>(hp + sn * HID));
      ax += w * f.x;
      ay += w * f.y;
    }
  }
  for (; i < e; ++i) {
    int2 p = csr_ew[i];
    int sn = p.x;
    float w = __uint_as_float((unsigned)p.y);
    float2 f = __half22float2(*reinterpret_cast<const __half2*>(hp + sn * HID));
    ax += w * f.x;
    ay += w * f.y;
  }
  unsigned short hx = f32_to_bf16_rne(ax);
  unsigned short lx = f32_to_bf16_rne(ax - bf16_to_f32(hx));
  unsigned short hy = f32_to_bf16_rne(ay);
  unsigned short ly = f32_to_bf16_rne(ay - bf16_to_f32(hy));
  ushort2 hv2 = {hx, hy}, lv2 = {lx, ly};
  *reinterpret_cast<ushort2*>(aggh + wid * HID + lane * 2) = hv2;
  *reinterpret_cast<ushort2*>(aggl + wid * HID + lane * 2) = lv2;
}

// ---------------- per-layer: h = relu(agg @ W^T + b * wsum) via split-bf16 MFMA ----------
// wave = 16 nodes x 128 outputs, K=128. a*w ~= ah*wh + ah*wl + al*wh (fp32 acc).
// D: col(kout)=lane&15, row(node)=(lane>>4)*4+reg  [guide §3, m89-verified].
__global__ void __launch_bounds__(256) mfma_linear_kernel(
    const unsigned short* __restrict__ aggh, const unsigned short* __restrict__ aggl,
    const unsigned short* __restrict__ whi, const unsigned short* __restrict__ wlo,
    const float* __restrict__ wsum, const float* __restrict__ b, __half* __restrict__ h) {
  int wave = threadIdx.x >> 6;
  int lane = threadIdx.x & 63;
  int node0 = blockIdx.x * 64 + wave * 16;
  int mrow = lane & 15;
  int kc = (lane >> 4) * 8;

  const unsigned short* pah = aggh + (node0 + mrow) * HID;
  const unsigned short* pal = aggl + (node0 + mrow) * HID;

  f32x4 acc[8];
#pragma unroll
  for (int t = 0; t < 8; ++t) acc[t] = (f32x4){0.f, 0.f, 0.f, 0.f};

#pragma unroll
  for (int s = 0; s < 4; ++s) {
    int joff = s * 32 + kc;
    bf16x8 ah = *reinterpret_cast<const bf16x8*>(pah + joff);
    bf16x8 al = *reinterpret_cast<const bf16x8*>(pal + joff);
#pragma unroll
    for (int t = 0; t < 8; ++t) {
      bf16x8 bh = *reinterpret_cast<const bf16x8*>(whi + (t * 16 + mrow) * HID + joff);
      bf16x8 bl = *reinterpret_cast<const bf16x8*>(wlo + (t * 16 + mrow) * HID + joff);
      acc[t] = __builtin_amdgcn_mfma_f32_16x16x32_bf16(ah, bh, acc[t], 0, 0, 0);
      acc[t] = __builtin_amdgcn_mfma_f32_16x16x32_bf16(ah, bl, acc[t], 0, 0, 0);
      acc[t] = __builtin_amdgcn_mfma_f32_16x16x32_bf16(al, bh, acc[t], 0, 0, 0);
    }
  }

  int nodeBase = node0 + (lane >> 4) * 4;
  float ws4[4];
#pragma unroll
  for (int r = 0; r < 4; ++r) ws4[r] = wsum[nodeBase + r];
#pragma unroll
  for (int t = 0; t < 8; ++t) {
    int kout = t * 16 + mrow;
    float bk = b[kout];
#pragma unroll
    for (int r = 0; r < 4; ++r) {
      float v = acc[t][r] + bk * ws4[r];
      h[(nodeBase + r) * HID + kout] = __float2half(fmaxf(v, 0.f));
    }
  }
}

// ---------------- cluster softmax head (wave per node) ----------------
__global__ void cluster_kernel(const __half* __restrict__ h, const float* __restrict__ cW,
                               const float* __restrict__ cb, float* __restrict__ out) {
  int wid = (blockIdx.x * blockDim.x + threadIdx.x) >> 6;
  int lane = threadIdx.x & 63;
  if (wid >= NN) return;
  float h0 = __half2float(h[wid * HID + lane]);
  float h1 = __half2float(h[wid * HID + 64 + lane]);
  float logit[3];
#pragma unroll
  for (int c = 0; c < 3; ++c) {
    float p = h0 * cW[c * HID + lane] + h1 * cW[c * HID + 64 + lane];
#pragma unroll
    for (int off = 32; off > 0; off >>= 1) p += __shfl_xor(p, off, 64);
    logit[c] = p + cb[c];
  }
  if (lane == 0) {
    float m = fmaxf(logit[0], fmaxf(logit[1], logit[2]));
    float e0 = expf(logit[0] - m), e1 = expf(logit[1] - m), e2 = expf(logit[2] - m);
    float inv = 1.0f / (e0 + e1 + e2);
    out[wid * 3 + 0] = e0 * inv;
    out[wid * 3 + 1] = e1 * inv;
    out[wid * 3 + 2] = e2 * inv;
  }
}

// ---------------- energy head: two-stage column reduction ----------------
__global__ void colsum_part_kernel(const __half* __restrict__ h, float* __restrict__ partial) {
  int t = threadIdx.x;
  int col = t & 127;
  int lane_id = blockIdx.x * 2 + (t >> 7);  // [0, 2048)
  float acc = 0.f;
  for (int r = lane_id; r < NN; r += 2048) acc += __half2float(h[r * HID + col]);
  partial[lane_id * HID + col] = acc;
}

__global__ void energy_final_kernel(const float* __restrict__ partial,
                                    const float* __restrict__ eW, const float* __restrict__ eb,
                                    float* __restrict__ out) {
  __shared__ float sh[8][HID];
  __shared__ float red[2];
  int t = threadIdx.x;
  int col = t & 127;
  int slot = t >> 7;  // 0..7
  float acc = 0.f;
  for (int i = 0; i < 256; ++i) acc += partial[(slot + 8 * i) * HID + col];
  sh[slot][col] = acc;
  __syncthreads();
  if (t < 128) {
    float s = 0.f;
#pragma unroll
    for (int j = 0; j < 8; ++j) s += sh[j][t];
    float v = s * (1.0f / NN) * eW[t];
#pragma unroll
    for (int off = 32; off > 0; off >>= 1) v += __shfl_xor(v, off, 64);
    if ((t & 63) == 0) red[t >> 6] = v;
  }
  __syncthreads();
  if (t == 0) {
    float e = red[0] + red[1] + eb[0];
    out[NN * 3] = e;
    out[NN * 3 + 1] = (e < -1.0f) ? 1.0f : 0.0f;
  }
}

extern "C" void kernel_launch(void* const* d_in, const int* in_sizes, int n_in,
                              void* d_out, int out_size, void* d_ws, size_t ws_size,
                              hipStream_t stream) {
  const float* x    = (const float*)d_in[0];
  const int*   ei   = (const int*)d_in[1];
  const float* dist = (const float*)d_in[2];
  const float* encW = (const float*)d_in[3];
  const float* encb = (const float*)d_in[4];
  const float* convW = (const float*)d_in[5];
  const float* convb = (const float*)d_in[6];
  const float* cW   = (const float*)d_in[7];
  const float* cb   = (const float*)d_in[8];
  const float* eW   = (const float*)d_in[9];
  const float* eb   = (const float*)d_in[10];
  float* out = (float*)d_out;

  // workspace layout (bytes)
  char* ws = (char*)d_ws;
  __half*         h       = (__half*)        (ws + 0);           // 10,240,000
  unsigned short* aggh    = (unsigned short*)(ws + 10240000);    // 10,240,000
  unsigned short* aggl    = (unsigned short*)(ws + 20480000);    // 10,240,000
  int2*           csr_ew  = (int2*)          (ws + 30720000);    //  5,120,000
  int*            row_ptr = (int*)           (ws + 35840000);    //    160,064
  int*            cnt     = (int*)           (ws + 36000064);    //    160,000
  float*          wsum    = (float*)         (ws + 36160064);    //    160,000
  unsigned short* whi5    = (unsigned short*)(ws + 36320064);    //    163,840
  unsigned short* wlo5    = (unsigned short*)(ws + 36483904);    //    163,840
  int*            rank    = (int*)           (ws + 36647744);    //  2,560,000
  if (ws_size < (size_t)39207744) return;  // insufficient scratch — fail visibly

  // aggh region is dead until the first aggregate -> scan scratch lives there;
  // and dead again after the last mfma_linear -> colsum partials live there.
  int*   blocksum = (int*)aggh;
  int*   blockoff = (int*)aggh + 512;
  float* partial  = (float*)aggh;  // 2048*128 floats = 1 MB

  const int* srcI = ei;
  const int* dstI = ei + NE;

  hipMemsetAsync(cnt, 0, 160000, stream);

  encoder_kernel<<<(NN * HID + 255) / 256, 256, 0, stream>>>(x, encW, encb, h);
  wconv_kernel<<<(NL * HID * HID + 255) / 256, 256, 0, stream>>>(convW, whi5, wlo5);

  hist_kernel<<<(NE + 255) / 256, 256, 0, stream>>>(dstI, cnt, rank);
  partial_kernel<<<NBLK, 256, 0, stream>>>(cnt, blocksum);
  scan_small_kernel<<<1, 256, 0, stream>>>(blocksum, blockoff, row_ptr);
  rowptr_kernel<<<NBLK, 256, 0, stream>>>(cnt, blockoff, row_ptr);
  scatter_kernel<<<(NE + 255) / 256, 256, 0, stream>>>(srcI, dstI, dist, row_ptr, rank, csr_ew);
  wsum_kernel<<<(NN + 255) / 256, 256, 0, stream>>>(row_ptr, csr_ew, wsum);

  for (int l = 0; l < NL; ++l) {
    aggregate_kernel<<<(NN * 64 + 255) / 256, 256, 0, stream>>>(h, row_ptr, csr_ew, aggh, aggl);
    mfma_linear_kernel<<<NN / 64, 256, 0, stream>>>(aggh, aggl,
                                                    whi5 + (size_t)l * HID * HID,
                                                    wlo5 + (size_t)l * HID * HID,
                                                    wsum, convb + (size_t)l * HID, h);
  }

  cluster_kernel<<<(NN * 64 + 255) / 256, 256, 0, stream>>>(h, cW, cb, out);
  colsum_part_kernel<<<1024, 256, 0, stream>>>(h, partial);
  energy_final_kernel<<<1, 1024, 0, stream>>>(partial, eW, eb, out);
}